// Round 2
// baseline (1696.029 us; speedup 1.0000x reference)
//
#include <hip/hip_runtime.h>
#include <hip/hip_bf16.h>

#define LOOK   1024
#define PREDN  256
#define TOT    1280
#define DPD    128
#define NK     971        // number of keys (T)
#define RPB    61         // valid q-rows per block (4 blocks/pair, 4*61 = 244)
#define SCALE  0.08838834764831845f  // 1/sqrt(128)

// =====================================================================
// Kernel A: fused window projection + PE + LayerNorm + flash attention.
// grid = 2048 (pair = bid>>2, row-quarter = bid&3), block = 256.
// LDS ~74.25 KB -> 2 blocks/CU.
// =====================================================================
__global__ __launch_bounds__(256, 2)
void attn_kernel(const float* __restrict__ lookback,
                 const float* __restrict__ focal,
                 const float* __restrict__ Wp,
                 const float* __restrict__ bp,
                 const float* __restrict__ pe,
                 const float* __restrict__ lng,
                 const float* __restrict__ lnb,
                 float* __restrict__ flat)
{
    __shared__ float s_series[TOT];
    __shared__ float s_q[64 * 132];    // q rows [64][e], stride 132 (16B-aligned rows)
    __shared__ float s_kT[128 * 36];   // k transposed [e][key], stride 36
    __shared__ float s_P[64 * 36];     // probs [row][key], stride 36
    __shared__ float s_x[32 * 68];     // td_next tile [key][d], stride 68
    __shared__ float s_m[64];
    __shared__ float s_l[64];
    __shared__ float s_al[64];

    const int t     = threadIdx.x;
    const int pair  = blockIdx.x >> 2;
    const int hb    = blockIdx.x & 3;
    const int lane  = t & 63;
    const int wave  = t >> 6;
    const int ecol  = t & 127;   // e-column for projection
    const int half2 = t >> 7;    // 0/1

    // ---- stage series (lookback ++ focal) ----
    {
        const float4* lb = (const float4*)(lookback + pair * LOOK);
        const float4* fc = (const float4*)(focal + pair * PREDN);
        float4* ss = (float4*)s_series;
        ss[t] = lb[t];                      // 256 * 4 = 1024 floats
        if (t < 64) ss[256 + t] = fc[t];    // 256 floats
    }

    // ---- per-thread caches (global, L2-hot) ----
    float Wreg[64];
    #pragma unroll
    for (int d = 0; d < 64; ++d) Wreg[d] = Wp[d * DPD + ecol];
    const float breg = bp[ecol];
    const float gA = lng[lane], gB = lng[lane + 64];
    const float bAc = lnb[lane], bBc = lnb[lane + 64];
    __syncthreads();

    // ---- q projection: local rows r = 2j + half2 ----
    {
        const int baseq = 972 + hb * RPB + half2;
        #pragma unroll
        for (int hh = 0; hh < 2; ++hh) {       // two groups of 16 rows
            float acc[16];
            #pragma unroll
            for (int i = 0; i < 16; ++i) acc[i] = breg;
            const int base2 = baseq + 32 * hh;
            #pragma unroll
            for (int dc = 0; dc < 64; dc += 16) {
                float S[46];
                #pragma unroll
                for (int u = 0; u < 46; ++u) {
                    int idx = base2 + dc + u;
                    S[u] = s_series[idx < TOT ? idx : TOT - 1];  // clamp only pad rows
                }
                #pragma unroll
                for (int i = 0; i < 16; ++i)
                    #pragma unroll
                    for (int d = 0; d < 16; ++d)
                        acc[i] += S[2 * i + d] * Wreg[dc + d];
            }
            #pragma unroll
            for (int i = 0; i < 16; ++i) {
                int r  = 2 * (16 * hh + i) + half2;      // local row
                int rg = hb * RPB + r;                   // global row (may be pad)
                s_q[r * 132 + ecol] = acc[i] + pe[(NK + rg) * DPD + ecol];
            }
        }
    }
    __syncthreads();

    // ---- LayerNorm q: one wave per row ----
    for (int r = wave; r < 64; r += 4) {
        float x0 = s_q[r * 132 + lane];
        float x1 = s_q[r * 132 + lane + 64];
        float sm = x0 + x1, sq = x0 * x0 + x1 * x1;
        #pragma unroll
        for (int o = 1; o < 64; o <<= 1) {
            sm += __shfl_xor(sm, o);
            sq += __shfl_xor(sq, o);
        }
        float mean = sm * (1.0f / 128.0f);
        float var  = sq * (1.0f / 128.0f) - mean * mean;
        float rs   = rsqrtf(var + 1e-5f);
        s_q[r * 132 + lane]      = (x0 - mean) * rs * gA + bAc;
        s_q[r * 132 + lane + 64] = (x1 - mean) * rs * gB + bBc;
    }
    if (t < 64) { s_m[t] = -3.0e38f; s_l[t] = 0.0f; }
    __syncthreads();

    // ---- main loop over key tiles ----
    float pv[16];
    #pragma unroll
    for (int i = 0; i < 16; ++i) pv[i] = 0.0f;

    for (int tile = 0; tile < 31; ++tile) {
        const int j0 = tile * 32;

        // -- phase 1: k projection (keys j0 + 2i + half2) --
        {
            float acc[16];
            #pragma unroll
            for (int i = 0; i < 16; ++i) acc[i] = breg;
            const int base2 = j0 + half2;
            #pragma unroll
            for (int dc = 0; dc < 64; dc += 16) {
                float S[46];
                #pragma unroll
                for (int u = 0; u < 46; ++u) S[u] = s_series[base2 + dc + u];
                #pragma unroll
                for (int i = 0; i < 16; ++i)
                    #pragma unroll
                    for (int d = 0; d < 16; ++d)
                        acc[i] += S[2 * i + d] * Wreg[dc + d];
            }
            #pragma unroll
            for (int i = 0; i < 16; ++i) {
                int key = j0 + 2 * i + half2;   // may be >= NK (masked at logits)
                s_kT[ecol * 36 + 2 * i + half2] = acc[i] + pe[key * DPD + ecol];
            }
        }
        __syncthreads();

        // -- phase 2: LayerNorm k (one wave per key) --
        #pragma unroll
        for (int kk = 0; kk < 8; ++kk) {
            int key = wave + 4 * kk;
            float x0 = s_kT[lane * 36 + key];
            float x1 = s_kT[(lane + 64) * 36 + key];
            float sm = x0 + x1, sq = x0 * x0 + x1 * x1;
            #pragma unroll
            for (int o = 1; o < 64; o <<= 1) {
                sm += __shfl_xor(sm, o);
                sq += __shfl_xor(sq, o);
            }
            float mean = sm * (1.0f / 128.0f);
            float var  = sq * (1.0f / 128.0f) - mean * mean;
            float rs   = rsqrtf(var + 1e-5f);
            s_kT[lane * 36 + key]        = (x0 - mean) * rs * gA + bAc;
            s_kT[(lane + 64) * 36 + key] = (x1 - mean) * rs * gB + bBc;
        }
        __syncthreads();

        // -- phase 3: logits + online softmax state + P store + x stage --
        {
            const int tg = wave >> 1, bq = wave & 1;
            const int tr = (t >> 3) & 7, tj = t & 7;
            const int R0 = 32 * tg + 8 * bq + tr;
            const int R1 = R0 + 16;
            float a0[4] = {0, 0, 0, 0}, a1[4] = {0, 0, 0, 0};
            #pragma unroll
            for (int g = 0; g < 32; ++g) {
                float4 q0 = *(const float4*)&s_q[R0 * 132 + 4 * g];
                float4 q1 = *(const float4*)&s_q[R1 * 132 + 4 * g];
                float qe0[4] = {q0.x, q0.y, q0.z, q0.w};
                float qe1[4] = {q1.x, q1.y, q1.z, q1.w};
                #pragma unroll
                for (int e = 0; e < 4; ++e) {
                    float4 kv = *(const float4*)&s_kT[(4 * g + e) * 36 + 4 * tj];
                    a0[0] += qe0[e] * kv.x; a0[1] += qe0[e] * kv.y;
                    a0[2] += qe0[e] * kv.z; a0[3] += qe0[e] * kv.w;
                    a1[0] += qe1[e] * kv.x; a1[1] += qe1[e] * kv.y;
                    a1[2] += qe1[e] * kv.z; a1[3] += qe1[e] * kv.w;
                }
            }
            float S0[4], S1[4];
            #pragma unroll
            for (int m2 = 0; m2 < 4; ++m2) {
                bool v = (j0 + 4 * tj + m2) < NK;
                S0[m2] = v ? a0[m2] * SCALE : -1e30f;
                S1[m2] = v ? a1[m2] * SCALE : -1e30f;
            }
            float mx0 = fmaxf(fmaxf(S0[0], S0[1]), fmaxf(S0[2], S0[3]));
            float mx1 = fmaxf(fmaxf(S1[0], S1[1]), fmaxf(S1[2], S1[3]));
            #pragma unroll
            for (int o = 1; o < 8; o <<= 1) {
                mx0 = fmaxf(mx0, __shfl_xor(mx0, o, 8));
                mx1 = fmaxf(mx1, __shfl_xor(mx1, o, 8));
            }
            float mo0 = s_m[R0], mo1 = s_m[R1];
            float mn0 = fmaxf(mo0, mx0), mn1 = fmaxf(mo1, mx1);
            float al0 = __expf(mo0 - mn0), al1 = __expf(mo1 - mn1);
            float p0[4], p1[4];
            float sm0 = 0.f, sm1 = 0.f;
            #pragma unroll
            for (int m2 = 0; m2 < 4; ++m2) {
                p0[m2] = __expf(S0[m2] - mn0); sm0 += p0[m2];
                p1[m2] = __expf(S1[m2] - mn1); sm1 += p1[m2];
            }
            #pragma unroll
            for (int o = 1; o < 8; o <<= 1) {
                sm0 += __shfl_xor(sm0, o, 8);
                sm1 += __shfl_xor(sm1, o, 8);
            }
            if (tj == 0) {
                s_m[R0] = mn0; s_l[R0] = s_l[R0] * al0 + sm0; s_al[R0] = al0;
                s_m[R1] = mn1; s_l[R1] = s_l[R1] * al1 + sm1; s_al[R1] = al1;
            }
            *(float4*)&s_P[R0 * 36 + 4 * tj] = make_float4(p0[0], p0[1], p0[2], p0[3]);
            *(float4*)&s_P[R1 * 36 + 4 * tj] = make_float4(p1[0], p1[1], p1[2], p1[3]);

            // stage x (td_next tile): x[jj][d] = series[j0 + jj + 1 + d]
            const int jj = t >> 3, dg8 = (t & 7) * 8;
            #pragma unroll
            for (int m2 = 0; m2 < 8; ++m2)
                s_x[jj * 68 + dg8 + m2] = s_series[j0 + jj + 1 + dg8 + m2];
        }
        __syncthreads();

        // -- phase 4: PV accumulate (rows {rq, rq+32}, d in [8dg, 8dg+8)) --
        {
            const int rq = t >> 3, dg = t & 7;
            const float al0 = s_al[rq], al1 = s_al[rq + 32];
            #pragma unroll
            for (int i = 0; i < 8; ++i) { pv[i] *= al0; pv[8 + i] *= al1; }
            #pragma unroll
            for (int g4 = 0; g4 < 8; ++g4) {
                float4 P0 = *(const float4*)&s_P[rq * 36 + 4 * g4];
                float4 P1 = *(const float4*)&s_P[(rq + 32) * 36 + 4 * g4];
                float pp0[4] = {P0.x, P0.y, P0.z, P0.w};
                float pp1[4] = {P1.x, P1.y, P1.z, P1.w};
                #pragma unroll
                for (int m2 = 0; m2 < 4; ++m2) {
                    float4 x0 = *(const float4*)&s_x[(4 * g4 + m2) * 68 + 8 * dg];
                    float4 x1 = *(const float4*)&s_x[(4 * g4 + m2) * 68 + 8 * dg + 4];
                    pv[0] += pp0[m2] * x0.x; pv[1] += pp0[m2] * x0.y;
                    pv[2] += pp0[m2] * x0.z; pv[3] += pp0[m2] * x0.w;
                    pv[4] += pp0[m2] * x1.x; pv[5] += pp0[m2] * x1.y;
                    pv[6] += pp0[m2] * x1.z; pv[7] += pp0[m2] * x1.w;
                    pv[8]  += pp1[m2] * x0.x; pv[9]  += pp1[m2] * x0.y;
                    pv[10] += pp1[m2] * x0.z; pv[11] += pp1[m2] * x0.w;
                    pv[12] += pp1[m2] * x1.x; pv[13] += pp1[m2] * x1.y;
                    pv[14] += pp1[m2] * x1.z; pv[15] += pp1[m2] * x1.w;
                }
            }
        }
        // no barrier needed here: next phase-1 writes only s_kT, synced after.
    }

    // ---- epilogue: normalize and store preds into flat workspace ----
    {
        const int rq = t >> 3, dg = t & 7;
        const float inv0 = 1.0f / s_l[rq];
        const float inv1 = 1.0f / s_l[rq + 32];
        float* dst0 = flat + pair * 15616 + (hb * RPB + rq) * 64 + 8 * dg;
        *(float4*)dst0       = make_float4(pv[0] * inv0, pv[1] * inv0, pv[2] * inv0, pv[3] * inv0);
        *(float4*)(dst0 + 4) = make_float4(pv[4] * inv0, pv[5] * inv0, pv[6] * inv0, pv[7] * inv0);
        if (rq + 32 < RPB) {
            float* dst1 = flat + pair * 15616 + (hb * RPB + rq + 32) * 64 + 8 * dg;
            *(float4*)dst1       = make_float4(pv[8] * inv1,  pv[9] * inv1,  pv[10] * inv1, pv[11] * inv1);
            *(float4*)(dst1 + 4) = make_float4(pv[12] * inv1, pv[13] * inv1, pv[14] * inv1, pv[15] * inv1);
        }
    }
}

// =====================================================================
// Kernel B: flat(512x15616) @ W1(15616x256) -> split-K partials.
// grid = 512 (8 m-tiles x 4 n-tiles x 16 k-splits), block = 256.
// =====================================================================
__global__ __launch_bounds__(256, 2)
void mlp1_kernel(const float* __restrict__ flat,
                 const float* __restrict__ W1,
                 float* __restrict__ part)
{
    const int bid = blockIdx.x;
    const int bm = bid & 7, bn = (bid >> 3) & 3, bz = bid >> 5;
    const int m0 = bm * 64, n0 = bn * 64;
    const int t0 = bz * 30 + (bz < 8 ? bz : 8);   // 488 k-tiles of 32 total
    const int nt = (bz < 8) ? 31 : 30;

    __shared__ float sA[64 * 36];
    __shared__ float sB[32 * 68];
    float acc[16];
    #pragma unroll
    for (int i = 0; i < 16; ++i) acc[i] = 0.0f;

    const int wv = threadIdx.x >> 6, ln = threadIdx.x & 63;
    const int tm = 4 * wv + (ln >> 4), tn = ln & 15;
    const int r = threadIdx.x >> 3;
    const int c4 = (threadIdx.x & 7) * 4;
    const int c8 = (threadIdx.x & 7) * 8;

    for (int tt = 0; tt < nt; ++tt) {
        const int kc = (t0 + tt) * 32;
        *(float4*)&sA[r * 36 + c4]        = *(const float4*)(flat + (m0 + r) * 15616 + kc + c4);
        *(float4*)&sA[(r + 32) * 36 + c4] = *(const float4*)(flat + (m0 + r + 32) * 15616 + kc + c4);
        *(float4*)&sB[r * 68 + c8]     = *(const float4*)(W1 + (kc + r) * 256 + n0 + c8);
        *(float4*)&sB[r * 68 + c8 + 4] = *(const float4*)(W1 + (kc + r) * 256 + n0 + c8 + 4);
        __syncthreads();
        #pragma unroll
        for (int kg = 0; kg < 8; ++kg) {
            float4 a[4], b[4];
            #pragma unroll
            for (int i = 0; i < 4; ++i) a[i] = *(const float4*)&sA[(4 * tm + i) * 36 + 4 * kg];
            #pragma unroll
            for (int j = 0; j < 4; ++j) b[j] = *(const float4*)&sB[(4 * kg + j) * 68 + 4 * tn];
            #pragma unroll
            for (int i = 0; i < 4; ++i) {
                acc[4*i+0] += a[i].x*b[0].x + a[i].y*b[1].x + a[i].z*b[2].x + a[i].w*b[3].x;
                acc[4*i+1] += a[i].x*b[0].y + a[i].y*b[1].y + a[i].z*b[2].y + a[i].w*b[3].y;
                acc[4*i+2] += a[i].x*b[0].z + a[i].y*b[1].z + a[i].z*b[2].z + a[i].w*b[3].z;
                acc[4*i+3] += a[i].x*b[0].w + a[i].y*b[1].w + a[i].z*b[2].w + a[i].w*b[3].w;
            }
        }
        __syncthreads();
    }
    float* dst = part + bz * (512 * 256);
    #pragma unroll
    for (int i = 0; i < 4; ++i)
        *(float4*)&dst[(m0 + 4 * tm + i) * 256 + n0 + 4 * tn] =
            make_float4(acc[4*i+0], acc[4*i+1], acc[4*i+2], acc[4*i+3]);
}

// =====================================================================
// Kernel C: reduce 16 partials + bias + exact GELU -> H (512x256).
// =====================================================================
__global__ void gelu_kernel(const float* __restrict__ part,
                            const float* __restrict__ b1,
                            float* __restrict__ H)
{
    const int i = blockIdx.x * 256 + threadIdx.x;   // 131072 total
    float s = 0.0f;
    #pragma unroll
    for (int ks = 0; ks < 16; ++ks) s += part[ks * 131072 + i];
    s += b1[i & 255];
    H[i] = 0.5f * s * (1.0f + erff(s * 0.7071067811865475f));
}

// =====================================================================
// Kernel D: out = H(512x256) @ W2(256x256) + b2, store FLOAT32.
// grid = 32 (8 m-tiles x 4 n-tiles), block = 256.
// =====================================================================
__global__ __launch_bounds__(256, 2)
void mlp2_kernel(const float* __restrict__ H,
                 const float* __restrict__ W2,
                 const float* __restrict__ b2,
                 float* __restrict__ out)
{
    const int bm = blockIdx.x & 7, bn = blockIdx.x >> 3;
    const int m0 = bm * 64, n0 = bn * 64;
    __shared__ float sA[64 * 36];
    __shared__ float sB[32 * 68];
    float acc[16];
    #pragma unroll
    for (int i = 0; i < 16; ++i) acc[i] = 0.0f;

    const int wv = threadIdx.x >> 6, ln = threadIdx.x & 63;
    const int tm = 4 * wv + (ln >> 4), tn = ln & 15;
    const int r = threadIdx.x >> 3;
    const int c4 = (threadIdx.x & 7) * 4;
    const int c8 = (threadIdx.x & 7) * 8;

    for (int tt = 0; tt < 8; ++tt) {
        const int kc = tt * 32;
        *(float4*)&sA[r * 36 + c4]        = *(const float4*)(H + (m0 + r) * 256 + kc + c4);
        *(float4*)&sA[(r + 32) * 36 + c4] = *(const float4*)(H + (m0 + r + 32) * 256 + kc + c4);
        *(float4*)&sB[r * 68 + c8]     = *(const float4*)(W2 + (kc + r) * 256 + n0 + c8);
        *(float4*)&sB[r * 68 + c8 + 4] = *(const float4*)(W2 + (kc + r) * 256 + n0 + c8 + 4);
        __syncthreads();
        #pragma unroll
        for (int kg = 0; kg < 8; ++kg) {
            float4 a[4], b[4];
            #pragma unroll
            for (int i = 0; i < 4; ++i) a[i] = *(const float4*)&sA[(4 * tm + i) * 36 + 4 * kg];
            #pragma unroll
            for (int j = 0; j < 4; ++j) b[j] = *(const float4*)&sB[(4 * kg + j) * 68 + 4 * tn];
            #pragma unroll
            for (int i = 0; i < 4; ++i) {
                acc[4*i+0] += a[i].x*b[0].x + a[i].y*b[1].x + a[i].z*b[2].x + a[i].w*b[3].x;
                acc[4*i+1] += a[i].x*b[0].y + a[i].y*b[1].y + a[i].z*b[2].y + a[i].w*b[3].y;
                acc[4*i+2] += a[i].x*b[0].z + a[i].y*b[1].z + a[i].z*b[2].z + a[i].w*b[3].z;
                acc[4*i+3] += a[i].x*b[0].w + a[i].y*b[1].w + a[i].z*b[2].w + a[i].w*b[3].w;
            }
        }
        __syncthreads();
    }
    #pragma unroll
    for (int i = 0; i < 4; ++i)
        #pragma unroll
        for (int j = 0; j < 4; ++j) {
            const int m = m0 + 4 * tm + i, n = n0 + 4 * tn + j;
            out[m * 256 + n] = acc[4 * i + j] + b2[n];
        }
}

extern "C" void kernel_launch(void* const* d_in, const int* in_sizes, int n_in,
                              void* d_out, int out_size, void* d_ws, size_t ws_size,
                              hipStream_t stream) {
    (void)in_sizes; (void)n_in; (void)out_size; (void)ws_size;
    const float* lookback = (const float*)d_in[0];
    const float* focal    = (const float*)d_in[1];
    const float* Wp       = (const float*)d_in[2];
    const float* bp       = (const float*)d_in[3];
    const float* pe       = (const float*)d_in[4];
    const float* lng      = (const float*)d_in[5];
    const float* lnb      = (const float*)d_in[6];
    const float* W1       = (const float*)d_in[7];
    const float* b1       = (const float*)d_in[8];
    const float* W2       = (const float*)d_in[9];
    const float* b2       = (const float*)d_in[10];

    float* flat = (float*)d_ws;                   // 512*15616 floats (32 MB)
    float* part = flat + 512 * 15616;             // 16*512*256 floats (8 MB)
    float* H    = part + 16 * 512 * 256;          // 512*256 floats

    hipLaunchKernelGGL(attn_kernel, dim3(2048), dim3(256), 0, stream,
                       lookback, focal, Wp, bp, pe, lng, lnb, flat);
    hipLaunchKernelGGL(mlp1_kernel, dim3(512), dim3(256), 0, stream, flat, W1, part);
    hipLaunchKernelGGL(gelu_kernel, dim3(512), dim3(256), 0, stream, part, b1, H);
    hipLaunchKernelGGL(mlp2_kernel, dim3(32), dim3(256), 0, stream, H, W2, b2,
                       (float*)d_out);
}

// Round 5
// 876.521 us; speedup vs baseline: 1.9350x; 1.9350x over previous
//
#include <hip/hip_runtime.h>
#include <hip/hip_bf16.h>

#define LOOK   1024
#define PREDN  256
#define TOT    1280
#define DPD    128
#define NK     971        // number of keys (T)
#define RPB    122        // valid q-rows per block (2 blocks/pair)
#define NTILES 31         // 31*32 = 992 keys >= 971
#define SCALE  0.08838834764831845f  // 1/sqrt(128)

typedef __attribute__((ext_vector_type(8))) short short8;
typedef __attribute__((ext_vector_type(4))) float f32x4;

// =====================================================================
// Kernel A: fused window projection + PE + LayerNorm + flash attention.
// grid = 1024 (pair = bid>>1, half = bid&1), block = 256 (4 waves).
// Wave w owns q-rows 32w..32w+31 (2 MFMA m-tiles). QK^T and PV are bf16
// MFMA 16x16x32; projection + LN stay fp32 VALU.
// LDS = 80384 B -> 2 blocks/CU (160,768 B <= 163,840 B per CU).
// =====================================================================
__global__ __launch_bounds__(256, 2)
void attn_kernel(const float* __restrict__ lookback,
                 const float* __restrict__ focal,
                 const float* __restrict__ Wp,
                 const float* __restrict__ bp,
                 const float* __restrict__ pe,
                 const float* __restrict__ lng,
                 const float* __restrict__ lnb,
                 float* __restrict__ flat)
{
    __shared__ float          s_series[TOT];          //  5120 B
    __shared__ float          s_scratch[32 * 128];    // 16384 B (proj staging)
    __shared__ __hip_bfloat16 s_qb[128 * 136];        // 34816 B (q bf16, frag layout)
    __shared__ __hip_bfloat16 s_kb[32 * 136];         //  8704 B (k bf16)
    __shared__ __hip_bfloat16 s_P[128 * 40];          // 10240 B (probs bf16)
    __shared__ __hip_bfloat16 s_xb[64 * 40];          //  5120 B (x^T: [d][key])

    const int t     = threadIdx.x;
    const int pair  = blockIdx.x >> 1;
    const int hb    = blockIdx.x & 1;
    const int lane  = t & 63;
    const int wave  = t >> 6;
    const int ecol  = t & 127;   // e-column for projection
    const int half2 = t >> 7;    // 0/1
    const int quad  = lane >> 4;
    const int kcol  = lane & 15;

    // ---- stage series (lookback ++ focal) ----
    {
        const float4* lb = (const float4*)(lookback + pair * LOOK);
        const float4* fc = (const float4*)(focal + pair * PREDN);
        float4* ss = (float4*)s_series;
        ss[t] = lb[t];
        if (t < 64) ss[256 + t] = fc[t];
    }

    // ---- per-thread caches ----
    float Wreg[64];
    #pragma unroll
    for (int d = 0; d < 64; ++d) Wreg[d] = Wp[d * DPD + ecol];
    const float breg = bp[ecol];
    const float gA = lng[lane], gB = lng[lane + 64];
    const float bAc = lnb[lane], bBc = lnb[lane + 64];
    __syncthreads();

    // ================= q: project + LN in 4 chunks of 32 rows ==========
    for (int c = 0; c < 4; ++c) {
        // proj -> s_scratch (rows 2i+half2 of chunk)
        {
            const int base2 = 972 + hb * RPB + 32 * c + half2;
            float acc[16];
            #pragma unroll
            for (int i = 0; i < 16; ++i) acc[i] = breg;
            #pragma unroll
            for (int dc = 0; dc < 64; dc += 16) {
                float S[46];
                #pragma unroll
                for (int u = 0; u < 46; ++u) {
                    int idx = base2 + dc + u;
                    S[u] = s_series[idx < TOT ? idx : TOT - 1];  // clamp pad rows only
                }
                #pragma unroll
                for (int i = 0; i < 16; ++i)
                    #pragma unroll
                    for (int d = 0; d < 16; ++d)
                        acc[i] += S[2 * i + d] * Wreg[dc + d];
            }
            #pragma unroll
            for (int i = 0; i < 16; ++i) {
                int r  = 2 * i + half2;
                int qg = hb * RPB + 32 * c + r;   // may be pad (>=244); max 249
                // pe row 971+qg; MAXLEN=1280 so max 1220 is in-bounds (no clamp).
                s_scratch[r * 128 + ecol] = acc[i] + pe[(971 + qg) * DPD + ecol];
            }
        }
        __syncthreads();
        // LN -> s_qb (wave w rows w+4kk)
        #pragma unroll
        for (int kk = 0; kk < 8; ++kk) {
            int r = wave + 4 * kk;
            float x0 = s_scratch[r * 128 + lane];
            float x1 = s_scratch[r * 128 + lane + 64];
            float sm = x0 + x1, sq = x0 * x0 + x1 * x1;
            #pragma unroll
            for (int o = 1; o < 64; o <<= 1) {
                sm += __shfl_xor(sm, o);
                sq += __shfl_xor(sq, o);
            }
            float mean = sm * (1.0f / 128.0f);
            float var  = sq * (1.0f / 128.0f) - mean * mean;
            float rs   = rsqrtf(var + 1e-5f);
            s_qb[(32 * c + r) * 136 + lane]      = __float2bfloat16((x0 - mean) * rs * gA + bAc);
            s_qb[(32 * c + r) * 136 + lane + 64] = __float2bfloat16((x1 - mean) * rs * gB + bBc);
        }
        __syncthreads();
    }

    // ---- cache q A-fragments in registers (constant over key tiles) ----
    short8 aq[2][4];
    #pragma unroll
    for (int mt = 0; mt < 2; ++mt)
        #pragma unroll
        for (int kc = 0; kc < 4; ++kc)
            aq[mt][kc] = *(const short8*)&s_qb[(32 * wave + 16 * mt + kcol) * 136 + kc * 32 + quad * 8];

    // ---- online-softmax state + PV accumulators (registers) ----
    float mrow[2][4], lrow[2][4];
    f32x4 o[2][4];
    #pragma unroll
    for (int mt = 0; mt < 2; ++mt)
        #pragma unroll
        for (int r = 0; r < 4; ++r) {
            mrow[mt][r] = -3.0e38f; lrow[mt][r] = 0.0f;
            o[mt][r] = (f32x4){0.f, 0.f, 0.f, 0.f};
        }

    // ================= main loop over 32-key tiles =====================
    for (int tile = 0; tile < NTILES; ++tile) {
        const int j0 = tile * 32;

        // -- P1: project 32 keys -> s_scratch (fp32) --
        {
            const int base2 = j0 + half2;
            float acc[16];
            #pragma unroll
            for (int i = 0; i < 16; ++i) acc[i] = breg;
            #pragma unroll
            for (int dc = 0; dc < 64; dc += 16) {
                float S[46];
                #pragma unroll
                for (int u = 0; u < 46; ++u) S[u] = s_series[base2 + dc + u];
                #pragma unroll
                for (int i = 0; i < 16; ++i)
                    #pragma unroll
                    for (int d = 0; d < 16; ++d)
                        acc[i] += S[2 * i + d] * Wreg[dc + d];
            }
            #pragma unroll
            for (int i = 0; i < 16; ++i) {
                int r = 2 * i + half2;                    // local key
                s_scratch[r * 128 + ecol] = acc[i] + pe[(j0 + r) * DPD + ecol];
            }
        }
        __syncthreads();

        // -- P2: LN k -> s_kb; stage x^T -> s_xb --
        #pragma unroll
        for (int kk = 0; kk < 8; ++kk) {
            int r = wave + 4 * kk;
            float x0 = s_scratch[r * 128 + lane];
            float x1 = s_scratch[r * 128 + lane + 64];
            float sm = x0 + x1, sq = x0 * x0 + x1 * x1;
            #pragma unroll
            for (int o2 = 1; o2 < 64; o2 <<= 1) {
                sm += __shfl_xor(sm, o2);
                sq += __shfl_xor(sq, o2);
            }
            float mean = sm * (1.0f / 128.0f);
            float var  = sq * (1.0f / 128.0f) - mean * mean;
            float rs   = rsqrtf(var + 1e-5f);
            s_kb[r * 136 + lane]      = __float2bfloat16((x0 - mean) * rs * gA + bAc);
            s_kb[r * 136 + lane + 64] = __float2bfloat16((x1 - mean) * rs * gB + bBc);
        }
        {   // x^T[d][kk] = series[j0 + kk + 1 + d]; thread: d = t>>2, 8 keys
            const int d = t >> 2, k0 = (t & 3) * 8;
            #pragma unroll
            for (int u = 0; u < 8; ++u)
                s_xb[d * 40 + k0 + u] = __float2bfloat16(s_series[j0 + k0 + u + 1 + d]);
        }
        __syncthreads();

        // -- P3: QK MFMA + online softmax + P->LDS + PV MFMA --
        f32x4 sacc[2][2];
        #pragma unroll
        for (int mt = 0; mt < 2; ++mt)
            #pragma unroll
            for (int nt = 0; nt < 2; ++nt)
                sacc[mt][nt] = (f32x4){0.f, 0.f, 0.f, 0.f};
        #pragma unroll
        for (int kc = 0; kc < 4; ++kc) {
            short8 b0 = *(const short8*)&s_kb[(kcol)      * 136 + kc * 32 + quad * 8];
            short8 b1 = *(const short8*)&s_kb[(16 + kcol) * 136 + kc * 32 + quad * 8];
            #pragma unroll
            for (int mt = 0; mt < 2; ++mt) {
                sacc[mt][0] = __builtin_amdgcn_mfma_f32_16x16x32_bf16(aq[mt][kc], b0, sacc[mt][0], 0, 0, 0);
                sacc[mt][1] = __builtin_amdgcn_mfma_f32_16x16x32_bf16(aq[mt][kc], b1, sacc[mt][1], 0, 0, 0);
            }
        }

        const bool v0 = (j0 + kcol) < NK;
        const bool v1 = (j0 + 16 + kcol) < NK;
        float alf[2][4];
        #pragma unroll
        for (int mt = 0; mt < 2; ++mt) {
            #pragma unroll
            for (int r = 0; r < 4; ++r) {
                float S0 = v0 ? sacc[mt][0][r] * SCALE : -1.0e30f;
                float S1 = v1 ? sacc[mt][1][r] * SCALE : -1.0e30f;
                float mx = fmaxf(S0, S1);
                #pragma unroll
                for (int o2 = 1; o2 < 16; o2 <<= 1) mx = fmaxf(mx, __shfl_xor(mx, o2));
                float mo = mrow[mt][r];
                float mn = fmaxf(mo, mx);
                float a  = __expf(mo - mn);
                float p0 = __expf(S0 - mn);
                float p1 = __expf(S1 - mn);
                float s  = p0 + p1;
                #pragma unroll
                for (int o2 = 1; o2 < 16; o2 <<= 1) s += __shfl_xor(s, o2);
                lrow[mt][r] = lrow[mt][r] * a + s;
                mrow[mt][r] = mn;
                alf[mt][r]  = a;
                int prow = 32 * wave + 16 * mt + 4 * quad + r;
                s_P[prow * 40 + kcol]      = __float2bfloat16(p0);
                s_P[prow * 40 + 16 + kcol] = __float2bfloat16(p1);
            }
        }

        // PV: o[mt][nt] = alpha*o + P . X   (K = 32 keys, one chunk)
        short8 xb[4];
        #pragma unroll
        for (int nt = 0; nt < 4; ++nt)
            xb[nt] = *(const short8*)&s_xb[(nt * 16 + kcol) * 40 + quad * 8];
        #pragma unroll
        for (int mt = 0; mt < 2; ++mt) {
            short8 ap = *(const short8*)&s_P[(32 * wave + 16 * mt + kcol) * 40 + quad * 8];
            #pragma unroll
            for (int nt = 0; nt < 4; ++nt) {
                f32x4 cc = o[mt][nt];
                cc[0] *= alf[mt][0]; cc[1] *= alf[mt][1];
                cc[2] *= alf[mt][2]; cc[3] *= alf[mt][3];
                o[mt][nt] = __builtin_amdgcn_mfma_f32_16x16x32_bf16(ap, xb[nt], cc, 0, 0, 0);
            }
        }
        // no trailing barrier: next P1 writes only s_scratch (not read in P3);
        // s_kb/s_xb rewritten only after the P1->P2 barrier, which each wave
        // reaches only after finishing its own P3 (program order).
    }

    // ================= epilogue: normalize, store flat =================
    #pragma unroll
    for (int mt = 0; mt < 2; ++mt)
        #pragma unroll
        for (int r = 0; r < 4; ++r) {
            int brow = 32 * wave + 16 * mt + 4 * quad + r;
            if (brow < RPB) {
                float inv = 1.0f / lrow[mt][r];
                float* dst = flat + pair * 15616 + (hb * RPB + brow) * 64;
                #pragma unroll
                for (int nt = 0; nt < 4; ++nt)
                    dst[nt * 16 + kcol] = o[mt][nt][r] * inv;
            }
        }
}

// =====================================================================
// Kernel B: flat(512x15616) @ W1(15616x256) -> split-K partials.
// =====================================================================
__global__ __launch_bounds__(256, 2)
void mlp1_kernel(const float* __restrict__ flat,
                 const float* __restrict__ W1,
                 float* __restrict__ part)
{
    const int bid = blockIdx.x;
    const int bm = bid & 7, bn = (bid >> 3) & 3, bz = bid >> 5;
    const int m0 = bm * 64, n0 = bn * 64;
    const int t0 = bz * 30 + (bz < 8 ? bz : 8);   // 488 k-tiles of 32 total
    const int nt = (bz < 8) ? 31 : 30;

    __shared__ float sA[64 * 36];
    __shared__ float sB[32 * 68];
    float acc[16];
    #pragma unroll
    for (int i = 0; i < 16; ++i) acc[i] = 0.0f;

    const int wv = threadIdx.x >> 6, ln = threadIdx.x & 63;
    const int tm = 4 * wv + (ln >> 4), tn = ln & 15;
    const int r = threadIdx.x >> 3;
    const int c4 = (threadIdx.x & 7) * 4;
    const int c8 = (threadIdx.x & 7) * 8;

    for (int tt = 0; tt < nt; ++tt) {
        const int kc = (t0 + tt) * 32;
        *(float4*)&sA[r * 36 + c4]        = *(const float4*)(flat + (m0 + r) * 15616 + kc + c4);
        *(float4*)&sA[(r + 32) * 36 + c4] = *(const float4*)(flat + (m0 + r + 32) * 15616 + kc + c4);
        *(float4*)&sB[r * 68 + c8]     = *(const float4*)(W1 + (kc + r) * 256 + n0 + c8);
        *(float4*)&sB[r * 68 + c8 + 4] = *(const float4*)(W1 + (kc + r) * 256 + n0 + c8 + 4);
        __syncthreads();
        #pragma unroll
        for (int kg = 0; kg < 8; ++kg) {
            float4 a[4], b[4];
            #pragma unroll
            for (int i = 0; i < 4; ++i) a[i] = *(const float4*)&sA[(4 * tm + i) * 36 + 4 * kg];
            #pragma unroll
            for (int j = 0; j < 4; ++j) b[j] = *(const float4*)&sB[(4 * kg + j) * 68 + 4 * tn];
            #pragma unroll
            for (int i = 0; i < 4; ++i) {
                acc[4*i+0] += a[i].x*b[0].x + a[i].y*b[1].x + a[i].z*b[2].x + a[i].w*b[3].x;
                acc[4*i+1] += a[i].x*b[0].y + a[i].y*b[1].y + a[i].z*b[2].y + a[i].w*b[3].y;
                acc[4*i+2] += a[i].x*b[0].z + a[i].y*b[1].z + a[i].z*b[2].z + a[i].w*b[3].z;
                acc[4*i+3] += a[i].x*b[0].w + a[i].y*b[1].w + a[i].z*b[2].w + a[i].w*b[3].w;
            }
        }
        __syncthreads();
    }
    float* dst = part + bz * (512 * 256);
    #pragma unroll
    for (int i = 0; i < 4; ++i)
        *(float4*)&dst[(m0 + 4 * tm + i) * 256 + n0 + 4 * tn] =
            make_float4(acc[4*i+0], acc[4*i+1], acc[4*i+2], acc[4*i+3]);
}

// =====================================================================
// Kernel C: reduce 16 partials + bias + exact GELU -> H (512x256).
// =====================================================================
__global__ void gelu_kernel(const float* __restrict__ part,
                            const float* __restrict__ b1,
                            float* __restrict__ H)
{
    const int i = blockIdx.x * 256 + threadIdx.x;
    float s = 0.0f;
    #pragma unroll
    for (int ks = 0; ks < 16; ++ks) s += part[ks * 131072 + i];
    s += b1[i & 255];
    H[i] = 0.5f * s * (1.0f + erff(s * 0.7071067811865475f));
}

// =====================================================================
// Kernel D: out = H(512x256) @ W2(256x256) + b2 (fp32 out).
// =====================================================================
__global__ __launch_bounds__(256, 2)
void mlp2_kernel(const float* __restrict__ H,
                 const float* __restrict__ W2,
                 const float* __restrict__ b2,
                 float* __restrict__ out)
{
    const int bm = blockIdx.x & 7, bn = blockIdx.x >> 3;
    const int m0 = bm * 64, n0 = bn * 64;
    __shared__ float sA[64 * 36];
    __shared__ float sB[32 * 68];
    float acc[16];
    #pragma unroll
    for (int i = 0; i < 16; ++i) acc[i] = 0.0f;

    const int wv = threadIdx.x >> 6, ln = threadIdx.x & 63;
    const int tm = 4 * wv + (ln >> 4), tn = ln & 15;
    const int r = threadIdx.x >> 3;
    const int c4 = (threadIdx.x & 7) * 4;
    const int c8 = (threadIdx.x & 7) * 8;

    for (int tt = 0; tt < 8; ++tt) {
        const int kc = tt * 32;
        *(float4*)&sA[r * 36 + c4]        = *(const float4*)(H + (m0 + r) * 256 + kc + c4);
        *(float4*)&sA[(r + 32) * 36 + c4] = *(const float4*)(H + (m0 + r + 32) * 256 + kc + c4);
        *(float4*)&sB[r * 68 + c8]     = *(const float4*)(W2 + (kc + r) * 256 + n0 + c8);
        *(float4*)&sB[r * 68 + c8 + 4] = *(const float4*)(W2 + (kc + r) * 256 + n0 + c8 + 4);
        __syncthreads();
        #pragma unroll
        for (int kg = 0; kg < 8; ++kg) {
            float4 a[4], b[4];
            #pragma unroll
            for (int i = 0; i < 4; ++i) a[i] = *(const float4*)&sA[(4 * tm + i) * 36 + 4 * kg];
            #pragma unroll
            for (int j = 0; j < 4; ++j) b[j] = *(const float4*)&sB[(4 * kg + j) * 68 + 4 * tn];
            #pragma unroll
            for (int i = 0; i < 4; ++i) {
                acc[4*i+0] += a[i].x*b[0].x + a[i].y*b[1].x + a[i].z*b[2].x + a[i].w*b[3].x;
                acc[4*i+1] += a[i].x*b[0].y + a[i].y*b[1].y + a[i].z*b[2].y + a[i].w*b[3].y;
                acc[4*i+2] += a[i].x*b[0].z + a[i].y*b[1].z + a[i].z*b[2].z + a[i].w*b[3].z;
                acc[4*i+3] += a[i].x*b[0].w + a[i].y*b[1].w + a[i].z*b[2].w + a[i].w*b[3].w;
            }
        }
        __syncthreads();
    }
    #pragma unroll
    for (int i = 0; i < 4; ++i)
        #pragma unroll
        for (int j = 0; j < 4; ++j) {
            const int m = m0 + 4 * tm + i, n = n0 + 4 * tn + j;
            out[m * 256 + n] = acc[4 * i + j] + b2[n];
        }
}

extern "C" void kernel_launch(void* const* d_in, const int* in_sizes, int n_in,
                              void* d_out, int out_size, void* d_ws, size_t ws_size,
                              hipStream_t stream) {
    (void)in_sizes; (void)n_in; (void)out_size; (void)ws_size;
    const float* lookback = (const float*)d_in[0];
    const float* focal    = (const float*)d_in[1];
    const float* Wp       = (const float*)d_in[2];
    const float* bp       = (const float*)d_in[3];
    const float* pe       = (const float*)d_in[4];
    const float* lng      = (const float*)d_in[5];
    const float* lnb      = (const float*)d_in[6];
    const float* W1       = (const float*)d_in[7];
    const float* b1       = (const float*)d_in[8];
    const float* W2       = (const float*)d_in[9];
    const float* b2       = (const float*)d_in[10];

    float* flat = (float*)d_ws;                   // 512*15616 floats (32 MB)
    float* part = flat + 512 * 15616;             // 16*512*256 floats (8 MB)
    float* H    = part + 16 * 512 * 256;          // 512*256 floats

    hipLaunchKernelGGL(attn_kernel, dim3(1024), dim3(256), 0, stream,
                       lookback, focal, Wp, bp, pe, lng, lnb, flat);
    hipLaunchKernelGGL(mlp1_kernel, dim3(512), dim3(256), 0, stream, flat, W1, part);
    hipLaunchKernelGGL(gelu_kernel, dim3(512), dim3(256), 0, stream, part, b1, H);
    hipLaunchKernelGGL(mlp2_kernel, dim3(32), dim3(256), 0, stream, H, W2, b2,
                       (float*)d_out);
}

// Round 8
// 621.244 us; speedup vs baseline: 2.7301x; 1.4109x over previous
//
#include <hip/hip_runtime.h>
#include <hip/hip_bf16.h>

#define LOOK   1024
#define PREDN  256
#define TOT    1280
#define SBLEN  1312       // padded bf16 series length (max read idx 1284)
#define DPD    128
#define NK     971        // number of keys (T)
#define RPB    122        // valid q-rows per block (2 blocks/pair)
#define NTILES 31         // 31*32 = 992 keys >= 971
#define SCALE  0.08838834764831845f  // 1/sqrt(128)

typedef __attribute__((ext_vector_type(8))) short short8;
typedef __attribute__((ext_vector_type(4))) float f32x4;

__device__ __forceinline__ unsigned short f2bu(float x) {
    union { __hip_bfloat16 b; unsigned short u; } v;
    v.b = __float2bfloat16(x);
    return v.u;
}

// Load 8 contiguous bf16 starting at series element idx0, using the two
// parity copies (s1[i] = s0[i+1]) so the base is always 4B-aligned.
__device__ __forceinline__ short8 load_sfrag(const unsigned short* s0,
                                             const unsigned short* s1,
                                             int idx0) {
    const int par = idx0 & 1;
    const unsigned int* p = (const unsigned int*)((par ? s1 : s0) + (idx0 - par));
    union { unsigned int u[4]; short8 s; } v;
    v.u[0] = p[0]; v.u[1] = p[1]; v.u[2] = p[2]; v.u[3] = p[3];
    return v.s;
}

// =====================================================================
// Kernel A: fused Hankel-MFMA projection + PE + LayerNorm + flash attn.
// grid = 1024 (pair = bid>>1, half = bid&1), block = 256 (4 waves).
// ALL matmuls (proj, QK^T, PV) on bf16 MFMA 16x16x32; LN/softmax VALU.
// LDS = 41088 B -> 3 blocks/CU.
// =====================================================================
__global__ __launch_bounds__(256, 3)
void attn_kernel(const float* __restrict__ lookback,
                 const float* __restrict__ focal,
                 const float* __restrict__ Wp,
                 const float* __restrict__ bp,
                 const float* __restrict__ pe,
                 const float* __restrict__ lng,
                 const float* __restrict__ lnb,
                 float* __restrict__ flat)
{
    __shared__ unsigned short s_sb0[SBLEN];        // series bf16, s_sb0[i]=s[i]
    __shared__ unsigned short s_sb1[SBLEN];        // shifted copy, s_sb1[i]=s[i+1]
    __shared__ float          s_scratch[32 * 132]; // 16896 B; overlaid by s_wpb at init
    __shared__ unsigned short s_kb[32 * 136];      //  8704 B (LN'd k-tile / q-chunk)
    __shared__ unsigned short s_P[128 * 40];       // 10240 B (probs bf16)

    const int t     = threadIdx.x;
    const int pair  = blockIdx.x >> 1;
    const int hb    = blockIdx.x & 1;
    const int lane  = t & 63;
    const int wave  = t >> 6;
    const int quad  = lane >> 4;
    const int kcol  = lane & 15;

    // ---------------- init: series bf16 copy0 + Wp^T bf16 (in s_scratch) ----
    unsigned short* s_wpb = (unsigned short*)s_scratch;  // [e][d], stride 64
    {
        const float4* lb = (const float4*)(lookback + pair * LOOK);
        if (t < 256) {
            float4 v = lb[t];
            s_sb0[4 * t]     = f2bu(v.x);
            s_sb0[4 * t + 1] = f2bu(v.y);
            s_sb0[4 * t + 2] = f2bu(v.z);
            s_sb0[4 * t + 3] = f2bu(v.w);
        }
        if (t < 64) {
            float4 v = ((const float4*)(focal + pair * PREDN))[t];
            s_sb0[LOOK + 4 * t]     = f2bu(v.x);
            s_sb0[LOOK + 4 * t + 1] = f2bu(v.y);
            s_sb0[LOOK + 4 * t + 2] = f2bu(v.z);
            s_sb0[LOOK + 4 * t + 3] = f2bu(v.w);
        }
        if (t < 32) s_sb0[TOT + t] = 0;            // zero tail (pad q windows)
        #pragma unroll
        for (int j = 0; j < 32; ++j) {             // Wp[k][e] -> s_wpb[e][k]
            int fl = j * 256 + t;                  // coalesced global read
            int k = fl >> 7, e = fl & 127;
            s_wpb[e * 64 + k] = f2bu(Wp[fl]);
        }
    }
    __syncthreads();

    // ---------------- init: copy1 + per-thread caches -----------------------
    {
        #pragma unroll
        for (int j = 0; j < 6; ++j) {
            int i = t + 256 * j;
            if (i < SBLEN - 1) s_sb1[i] = s_sb0[i + 1];
            else if (i == SBLEN - 1) s_sb1[i] = 0;
        }
    }
    // Wp B-frags: wave w owns n-tiles {2w, 2w+1}; [nt2][kc], kc = K-chunk of 64
    short8 wb[2][2];
    #pragma unroll
    for (int nt2 = 0; nt2 < 2; ++nt2) {
        int e = (2 * wave + nt2) * 16 + kcol;
        #pragma unroll
        for (int kc = 0; kc < 2; ++kc)
            wb[nt2][kc] = *(const short8*)&s_wpb[e * 64 + kc * 32 + quad * 8];
    }
    float bpv[2], gv[8], bv[8];
    #pragma unroll
    for (int nt2 = 0; nt2 < 2; ++nt2) bpv[nt2] = bp[(2 * wave + nt2) * 16 + kcol];
    #pragma unroll
    for (int u = 0; u < 8; ++u) { gv[u] = lng[kcol * 8 + u]; bv[u] = lnb[kcol * 8 + u]; }
    __syncthreads();   // s_wpb (=s_scratch) free from here

    // ---------------- q: 4 chunks of 32 rows (proj MFMA + LN) ---------------
    short8 aq[2][4];   // q A-frags for this wave's 32 rows (filled at c==wave)
    for (int c = 0; c < 4; ++c) {
        const int qb0 = 972 + hb * RPB + 32 * c;
        f32x4 pc[2][2];
        #pragma unroll
        for (int m = 0; m < 2; ++m)
            #pragma unroll
            for (int n = 0; n < 2; ++n) pc[m][n] = (f32x4){0.f, 0.f, 0.f, 0.f};
        #pragma unroll
        for (int m = 0; m < 2; ++m)
            #pragma unroll
            for (int kc = 0; kc < 2; ++kc) {
                short8 af = load_sfrag(s_sb0, s_sb1, qb0 + 16 * m + kcol + kc * 32 + quad * 8);
                #pragma unroll
                for (int nt2 = 0; nt2 < 2; ++nt2)
                    pc[m][nt2] = __builtin_amdgcn_mfma_f32_16x16x32_bf16(af, wb[nt2][kc], pc[m][nt2], 0, 0, 0);
            }
        #pragma unroll
        for (int m = 0; m < 2; ++m)
            #pragma unroll
            for (int nt2 = 0; nt2 < 2; ++nt2) {
                int e = (2 * wave + nt2) * 16 + kcol;
                #pragma unroll
                for (int r = 0; r < 4; ++r) {
                    int rl = 16 * m + quad * 4 + r;
                    int qg = hb * RPB + 32 * c + rl;   // pe row 971+qg <= 1220 < 1280
                    s_scratch[rl * 132 + e] = pc[m][nt2][r] + bpv[nt2] + pe[(971 + qg) * DPD + e];
                }
            }
        __syncthreads();
        // LN: 16 lanes per row, 2 passes
        #pragma unroll
        for (int p = 0; p < 2; ++p) {
            int row = wave * 8 + p * 4 + quad;
            float4 xa = *(const float4*)&s_scratch[row * 132 + kcol * 8];
            float4 xb2 = *(const float4*)&s_scratch[row * 132 + kcol * 8 + 4];
            float sm = xa.x + xa.y + xa.z + xa.w + xb2.x + xb2.y + xb2.z + xb2.w;
            float sq = xa.x*xa.x + xa.y*xa.y + xa.z*xa.z + xa.w*xa.w
                     + xb2.x*xb2.x + xb2.y*xb2.y + xb2.z*xb2.z + xb2.w*xb2.w;
            #pragma unroll
            for (int o2 = 1; o2 < 16; o2 <<= 1) {
                sm += __shfl_xor(sm, o2);
                sq += __shfl_xor(sq, o2);
            }
            float mean = sm * (1.0f / 128.0f);
            float var  = sq * (1.0f / 128.0f) - mean * mean;
            float rs   = rsqrtf(var + 1e-5f);
            float xs[8] = {xa.x, xa.y, xa.z, xa.w, xb2.x, xb2.y, xb2.z, xb2.w};
            short8 ov;
            #pragma unroll
            for (int u = 0; u < 8; ++u)
                ov[u] = (short)f2bu((xs[u] - mean) * rs * gv[u] + bv[u]);
            *(short8*)&s_kb[row * 136 + kcol * 8] = ov;
        }
        __syncthreads();
        if (wave == c) {   // this wave owns q rows 32c..32c+31
            #pragma unroll
            for (int mt = 0; mt < 2; ++mt)
                #pragma unroll
                for (int kc = 0; kc < 4; ++kc)
                    aq[mt][kc] = *(const short8*)&s_kb[(16 * mt + kcol) * 136 + kc * 32 + quad * 8];
        }
    }

    // ---- online-softmax state + PV accumulators ----
    float mrow[2][4], lrow[2][4];
    f32x4 o[2][4];
    #pragma unroll
    for (int mt = 0; mt < 2; ++mt)
        #pragma unroll
        for (int r = 0; r < 4; ++r) {
            mrow[mt][r] = -3.0e38f; lrow[mt][r] = 0.0f;
            o[mt][r] = (f32x4){0.f, 0.f, 0.f, 0.f};
        }

    // ================= main loop over 32-key tiles =====================
    for (int tile = 0; tile < NTILES; ++tile) {
        const int j0 = tile * 32;

        // -- P1: k-proj MFMA -> s_scratch (+bp +pe) --
        {
            f32x4 pc[2][2];
            #pragma unroll
            for (int m = 0; m < 2; ++m)
                #pragma unroll
                for (int n = 0; n < 2; ++n) pc[m][n] = (f32x4){0.f, 0.f, 0.f, 0.f};
            #pragma unroll
            for (int m = 0; m < 2; ++m)
                #pragma unroll
                for (int kc = 0; kc < 2; ++kc) {
                    short8 af = load_sfrag(s_sb0, s_sb1, j0 + 16 * m + kcol + kc * 32 + quad * 8);
                    #pragma unroll
                    for (int nt2 = 0; nt2 < 2; ++nt2)
                        pc[m][nt2] = __builtin_amdgcn_mfma_f32_16x16x32_bf16(af, wb[nt2][kc], pc[m][nt2], 0, 0, 0);
                }
            #pragma unroll
            for (int m = 0; m < 2; ++m)
                #pragma unroll
                for (int nt2 = 0; nt2 < 2; ++nt2) {
                    int e = (2 * wave + nt2) * 16 + kcol;
                    #pragma unroll
                    for (int r = 0; r < 4; ++r) {
                        int rl = 16 * m + quad * 4 + r;   // pe row j0+rl <= 991 < 1280
                        s_scratch[rl * 132 + e] = pc[m][nt2][r] + bpv[nt2] + pe[(j0 + rl) * DPD + e];
                    }
                }
        }
        __syncthreads();

        // -- P2: LN k -> s_kb --
        #pragma unroll
        for (int p = 0; p < 2; ++p) {
            int row = wave * 8 + p * 4 + quad;
            float4 xa = *(const float4*)&s_scratch[row * 132 + kcol * 8];
            float4 xb2 = *(const float4*)&s_scratch[row * 132 + kcol * 8 + 4];
            float sm = xa.x + xa.y + xa.z + xa.w + xb2.x + xb2.y + xb2.z + xb2.w;
            float sq = xa.x*xa.x + xa.y*xa.y + xa.z*xa.z + xa.w*xa.w
                     + xb2.x*xb2.x + xb2.y*xb2.y + xb2.z*xb2.z + xb2.w*xb2.w;
            #pragma unroll
            for (int o2 = 1; o2 < 16; o2 <<= 1) {
                sm += __shfl_xor(sm, o2);
                sq += __shfl_xor(sq, o2);
            }
            float mean = sm * (1.0f / 128.0f);
            float var  = sq * (1.0f / 128.0f) - mean * mean;
            float rs   = rsqrtf(var + 1e-5f);
            float xs[8] = {xa.x, xa.y, xa.z, xa.w, xb2.x, xb2.y, xb2.z, xb2.w};
            short8 ov;
            #pragma unroll
            for (int u = 0; u < 8; ++u)
                ov[u] = (short)f2bu((xs[u] - mean) * rs * gv[u] + bv[u]);
            *(short8*)&s_kb[row * 136 + kcol * 8] = ov;
        }
        __syncthreads();

        // -- P3: QK MFMA + online softmax + P->LDS + PV MFMA --
        f32x4 sacc[2][2];
        #pragma unroll
        for (int mt = 0; mt < 2; ++mt)
            #pragma unroll
            for (int nt = 0; nt < 2; ++nt)
                sacc[mt][nt] = (f32x4){0.f, 0.f, 0.f, 0.f};
        #pragma unroll
        for (int kc = 0; kc < 4; ++kc) {
            short8 b0 = *(const short8*)&s_kb[(kcol)      * 136 + kc * 32 + quad * 8];
            short8 b1 = *(const short8*)&s_kb[(16 + kcol) * 136 + kc * 32 + quad * 8];
            #pragma unroll
            for (int mt = 0; mt < 2; ++mt) {
                sacc[mt][0] = __builtin_amdgcn_mfma_f32_16x16x32_bf16(aq[mt][kc], b0, sacc[mt][0], 0, 0, 0);
                sacc[mt][1] = __builtin_amdgcn_mfma_f32_16x16x32_bf16(aq[mt][kc], b1, sacc[mt][1], 0, 0, 0);
            }
        }

        const bool v0 = (j0 + kcol) < NK;
        const bool v1 = (j0 + 16 + kcol) < NK;
        float alf[2][4];
        #pragma unroll
        for (int mt = 0; mt < 2; ++mt) {
            #pragma unroll
            for (int r = 0; r < 4; ++r) {
                float S0 = v0 ? sacc[mt][0][r] * SCALE : -1.0e30f;
                float S1 = v1 ? sacc[mt][1][r] * SCALE : -1.0e30f;
                float mx = fmaxf(S0, S1);
                #pragma unroll
                for (int o2 = 1; o2 < 16; o2 <<= 1) mx = fmaxf(mx, __shfl_xor(mx, o2));
                float mo = mrow[mt][r];
                float mn = fmaxf(mo, mx);
                float a  = __expf(mo - mn);
                float p0 = __expf(S0 - mn);
                float p1 = __expf(S1 - mn);
                float s  = p0 + p1;
                #pragma unroll
                for (int o2 = 1; o2 < 16; o2 <<= 1) s += __shfl_xor(s, o2);
                lrow[mt][r] = lrow[mt][r] * a + s;
                mrow[mt][r] = mn;
                alf[mt][r]  = a;
                int prow = 32 * wave + 16 * mt + 4 * quad + r;
                s_P[prow * 40 + kcol]      = f2bu(p0);
                s_P[prow * 40 + 16 + kcol] = f2bu(p1);
            }
        }

        // PV: B-frags straight from series bf16 (x[key][d] = s[j0+key+1+d])
        short8 xf[4];
        #pragma unroll
        for (int nt = 0; nt < 4; ++nt)
            xf[nt] = load_sfrag(s_sb0, s_sb1, j0 + 1 + nt * 16 + kcol + quad * 8);
        #pragma unroll
        for (int mt = 0; mt < 2; ++mt) {
            short8 ap = *(const short8*)&s_P[(32 * wave + 16 * mt + kcol) * 40 + quad * 8];
            #pragma unroll
            for (int nt = 0; nt < 4; ++nt) {
                f32x4 cc = o[mt][nt];
                cc[0] *= alf[mt][0]; cc[1] *= alf[mt][1];
                cc[2] *= alf[mt][2]; cc[3] *= alf[mt][3];
                o[mt][nt] = __builtin_amdgcn_mfma_f32_16x16x32_bf16(ap, xf[nt], cc, 0, 0, 0);
            }
        }
        // no trailing barrier: next P1 writes only s_scratch (not read in P3);
        // s_kb rewritten only after the P1 barrier; s_P is wave-local.
    }

    // ================= epilogue: normalize, store flat =================
    #pragma unroll
    for (int mt = 0; mt < 2; ++mt)
        #pragma unroll
        for (int r = 0; r < 4; ++r) {
            int brow = 32 * wave + 16 * mt + 4 * quad + r;
            if (brow < RPB) {
                float inv = 1.0f / lrow[mt][r];
                float* dst = flat + pair * 15616 + (hb * RPB + brow) * 64;
                #pragma unroll
                for (int nt = 0; nt < 4; ++nt)
                    dst[nt * 16 + kcol] = o[mt][nt][r] * inv;
            }
        }
}

// =====================================================================
// Kernel B: flat(512x15616) @ W1(15616x256) -> split-K partials.
// =====================================================================
__global__ __launch_bounds__(256, 2)
void mlp1_kernel(const float* __restrict__ flat,
                 const float* __restrict__ W1,
                 float* __restrict__ part)
{
    const int bid = blockIdx.x;
    const int bm = bid & 7, bn = (bid >> 3) & 3, bz = bid >> 5;
    const int m0 = bm * 64, n0 = bn * 64;
    const int t0 = bz * 30 + (bz < 8 ? bz : 8);   // 488 k-tiles of 32 total
    const int nt = (bz < 8) ? 31 : 30;

    __shared__ float sA[64 * 36];
    __shared__ float sB[32 * 68];
    float acc[16];
    #pragma unroll
    for (int i = 0; i < 16; ++i) acc[i] = 0.0f;

    const int wv = threadIdx.x >> 6, ln = threadIdx.x & 63;
    const int tm = 4 * wv + (ln >> 4), tn = ln & 15;
    const int r = threadIdx.x >> 3;
    const int c4 = (threadIdx.x & 7) * 4;
    const int c8 = (threadIdx.x & 7) * 8;

    for (int tt = 0; tt < nt; ++tt) {
        const int kc = (t0 + tt) * 32;
        *(float4*)&sA[r * 36 + c4]        = *(const float4*)(flat + (m0 + r) * 15616 + kc + c4);
        *(float4*)&sA[(r + 32) * 36 + c4] = *(const float4*)(flat + (m0 + r + 32) * 15616 + kc + c4);
        *(float4*)&sB[r * 68 + c8]     = *(const float4*)(W1 + (kc + r) * 256 + n0 + c8);
        *(float4*)&sB[r * 68 + c8 + 4] = *(const float4*)(W1 + (kc + r) * 256 + n0 + c8 + 4);
        __syncthreads();
        #pragma unroll
        for (int kg = 0; kg < 8; ++kg) {
            float4 a[4], b[4];
            #pragma unroll
            for (int i = 0; i < 4; ++i) a[i] = *(const float4*)&sA[(4 * tm + i) * 36 + 4 * kg];
            #pragma unroll
            for (int j = 0; j < 4; ++j) b[j] = *(const float4*)&sB[(4 * kg + j) * 68 + 4 * tn];
            #pragma unroll
            for (int i = 0; i < 4; ++i) {
                acc[4*i+0] += a[i].x*b[0].x + a[i].y*b[1].x + a[i].z*b[2].x + a[i].w*b[3].x;
                acc[4*i+1] += a[i].x*b[0].y + a[i].y*b[1].y + a[i].z*b[2].y + a[i].w*b[3].y;
                acc[4*i+2] += a[i].x*b[0].z + a[i].y*b[1].z + a[i].z*b[2].z + a[i].w*b[3].z;
                acc[4*i+3] += a[i].x*b[0].w + a[i].y*b[1].w + a[i].z*b[2].w + a[i].w*b[3].w;
            }
        }
        __syncthreads();
    }
    float* dst = part + bz * (512 * 256);
    #pragma unroll
    for (int i = 0; i < 4; ++i)
        *(float4*)&dst[(m0 + 4 * tm + i) * 256 + n0 + 4 * tn] =
            make_float4(acc[4*i+0], acc[4*i+1], acc[4*i+2], acc[4*i+3]);
}

// =====================================================================
// Kernel C: reduce 16 partials + bias + exact GELU -> H (512x256).
// =====================================================================
__global__ void gelu_kernel(const float* __restrict__ part,
                            const float* __restrict__ b1,
                            float* __restrict__ H)
{
    const int i = blockIdx.x * 256 + threadIdx.x;
    float s = 0.0f;
    #pragma unroll
    for (int ks = 0; ks < 16; ++ks) s += part[ks * 131072 + i];
    s += b1[i & 255];
    H[i] = 0.5f * s * (1.0f + erff(s * 0.7071067811865475f));
}

// =====================================================================
// Kernel D: out = H(512x256) @ W2(256x256) + b2 (fp32 out).
// =====================================================================
__global__ __launch_bounds__(256, 2)
void mlp2_kernel(const float* __restrict__ H,
                 const float* __restrict__ W2,
                 const float* __restrict__ b2,
                 float* __restrict__ out)
{
    const int bm = blockIdx.x & 7, bn = blockIdx.x >> 3;
    const int m0 = bm * 64, n0 = bn * 64;
    __shared__ float sA[64 * 36];
    __shared__ float sB[32 * 68];
    float acc[16];
    #pragma unroll
    for (int i = 0; i < 16; ++i) acc[i] = 0.0f;

    const int wv = threadIdx.x >> 6, ln = threadIdx.x & 63;
    const int tm = 4 * wv + (ln >> 4), tn = ln & 15;
    const int r = threadIdx.x >> 3;
    const int c4 = (threadIdx.x & 7) * 4;
    const int c8 = (threadIdx.x & 7) * 8;

    for (int tt = 0; tt < 8; ++tt) {
        const int kc = tt * 32;
        *(float4*)&sA[r * 36 + c4]        = *(const float4*)(H + (m0 + r) * 256 + kc + c4);
        *(float4*)&sA[(r + 32) * 36 + c4] = *(const float4*)(H + (m0 + r + 32) * 256 + kc + c4);
        *(float4*)&sB[r * 68 + c8]     = *(const float4*)(W2 + (kc + r) * 256 + n0 + c8);
        *(float4*)&sB[r * 68 + c8 + 4] = *(const float4*)(W2 + (kc + r) * 256 + n0 + c8 + 4);
        __syncthreads();
        #pragma unroll
        for (int kg = 0; kg < 8; ++kg) {
            float4 a[4], b[4];
            #pragma unroll
            for (int i = 0; i < 4; ++i) a[i] = *(const float4*)&sA[(4 * tm + i) * 36 + 4 * kg];
            #pragma unroll
            for (int j = 0; j < 4; ++j) b[j] = *(const float4*)&sB[(4 * kg + j) * 68 + 4 * tn];
            #pragma unroll
            for (int i = 0; i < 4; ++i) {
                acc[4*i+0] += a[i].x*b[0].x + a[i].y*b[1].x + a[i].z*b[2].x + a[i].w*b[3].x;
                acc[4*i+1] += a[i].x*b[0].y + a[i].y*b[1].y + a[i].z*b[2].y + a[i].w*b[3].y;
                acc[4*i+2] += a[i].x*b[0].z + a[i].y*b[1].z + a[i].z*b[2].z + a[i].w*b[3].z;
                acc[4*i+3] += a[i].x*b[0].w + a[i].y*b[1].w + a[i].z*b[2].w + a[i].w*b[3].w;
            }
        }
        __syncthreads();
    }
    #pragma unroll
    for (int i = 0; i < 4; ++i)
        #pragma unroll
        for (int j = 0; j < 4; ++j) {
            const int m = m0 + 4 * tm + i, n = n0 + 4 * tn + j;
            out[m * 256 + n] = acc[4 * i + j] + b2[n];
        }
}

extern "C" void kernel_launch(void* const* d_in, const int* in_sizes, int n_in,
                              void* d_out, int out_size, void* d_ws, size_t ws_size,
                              hipStream_t stream) {
    (void)in_sizes; (void)n_in; (void)out_size; (void)ws_size;
    const float* lookback = (const float*)d_in[0];
    const float* focal    = (const float*)d_in[1];
    const float* Wp       = (const float*)d_in[2];
    const float* bp       = (const float*)d_in[3];
    const float* pe       = (const float*)d_in[4];
    const float* lng      = (const float*)d_in[5];
    const float* lnb      = (const float*)d_in[6];
    const float* W1       = (const float*)d_in[7];
    const float* b1       = (const float*)d_in[8];
    const float* W2       = (const float*)d_in[9];
    const float* b2       = (const float*)d_in[10];

    float* flat = (float*)d_ws;                   // 512*15616 floats (32 MB)
    float* part = flat + 512 * 15616;             // 16*512*256 floats (8 MB)
    float* H    = part + 16 * 512 * 256;          // 512*256 floats

    hipLaunchKernelGGL(attn_kernel, dim3(1024), dim3(256), 0, stream,
                       lookback, focal, Wp, bp, pe, lng, lnb, flat);
    hipLaunchKernelGGL(mlp1_kernel, dim3(512), dim3(256), 0, stream, flat, W1, part);
    hipLaunchKernelGGL(gelu_kernel, dim3(512), dim3(256), 0, stream, part, b1, H);
    hipLaunchKernelGGL(mlp2_kernel, dim3(32), dim3(256), 0, stream, H, W2, b2,
                       (float*)d_out);
}

// Round 9
// 358.258 us; speedup vs baseline: 4.7341x; 1.7341x over previous
//
#include <hip/hip_runtime.h>
#include <hip/hip_bf16.h>

#define LOOK   1024
#define PREDN  256
#define TOT    1280
#define SBLEN  1296       // bf16 series + zero tail (max read elem 1285)
#define DPD    128
#define NK     971        // number of keys (T)
#define RPB    122        // valid q-rows per block (2 blocks/pair)
#define NKT    16         // 16 key-tiles of 64 (1024 >= 971)
#define SCALE  0.08838834764831845f  // 1/sqrt(128)

typedef __attribute__((ext_vector_type(8))) short short8;
typedef __attribute__((ext_vector_type(4))) float f32x4;

__device__ __forceinline__ unsigned short f2bu(float x) {
    union { __hip_bfloat16 b; unsigned short u; } v;
    v.b = __float2bfloat16(x);
    return v.u;
}
__device__ __forceinline__ unsigned int pack2(float a, float b) {
    return (unsigned int)f2bu(a) | ((unsigned int)f2bu(b) << 16);
}

// 8 contiguous bf16 from series at element idx0 (any parity): 5 dwords + funnel shift.
__device__ __forceinline__ short8 load_sfrag(const unsigned short* s0, int idx0) {
    const unsigned int* p = (const unsigned int*)s0 + (idx0 >> 1);
    const unsigned int sh = (idx0 & 1) << 4;
    unsigned int w0 = p[0], w1 = p[1], w2 = p[2], w3 = p[3], w4 = p[4];
    union { unsigned int u[4]; short8 s; } v;
    v.u[0] = (unsigned int)((((unsigned long long)w1 << 32) | w0) >> sh);
    v.u[1] = (unsigned int)((((unsigned long long)w2 << 32) | w1) >> sh);
    v.u[2] = (unsigned int)((((unsigned long long)w3 << 32) | w2) >> sh);
    v.u[3] = (unsigned int)((((unsigned long long)w4 << 32) | w3) >> sh);
    return v.s;
}
// 8 bf16 from LDS at 8B-aligned (not 16B) address: two b64 reads.
__device__ __forceinline__ short8 ld_b64x2(const unsigned short* p) {
    union { unsigned long long q[2]; short8 s; } v;
    v.q[0] = *(const unsigned long long*)p;
    v.q[1] = *(const unsigned long long*)(p + 4);
    return v.s;
}

// Fused projection of 64 rows (16 per wave) + pe' + in-register LN -> s_kb[row][e].
// D[m=e][n=row]: lane holds e = 16mt+4quad+r for row = rowkb (its kcol).
__device__ __forceinline__ void proj_tile(
    const unsigned short* s_sb0, const unsigned short* s_wpb,
    const float* s_g, const float* s_b, unsigned short* s_kb,
    const float* __restrict__ peb,
    int widx, int perow, int rowkb, int quad, int kcol)
{
    short8 bw0 = load_sfrag(s_sb0, widx + 8 * quad);        // d in [8q, 8q+8)
    short8 bw1 = load_sfrag(s_sb0, widx + 32 + 8 * quad);   // d in [32+8q, ...)
    f32x4 pc[8];
    #pragma unroll
    for (int mt = 0; mt < 8; ++mt) pc[mt] = (f32x4){0.f, 0.f, 0.f, 0.f};
    const int k7 = kcol & 7;
    #pragma unroll
    for (int mt = 0; mt < 8; ++mt) {
        int e = 16 * mt + kcol;
        short8 a0 = *(const short8*)&s_wpb[e * 64 + ((quad ^ k7) << 3)];
        short8 a1 = *(const short8*)&s_wpb[e * 64 + (((4 + quad) ^ k7) << 3)];
        pc[mt] = __builtin_amdgcn_mfma_f32_16x16x32_bf16(a0, bw0, pc[mt], 0, 0, 0);
        pc[mt] = __builtin_amdgcn_mfma_f32_16x16x32_bf16(a1, bw1, pc[mt], 0, 0, 0);
    }
    float x[8][4];
    float sm = 0.f, sq = 0.f;
    #pragma unroll
    for (int mt = 0; mt < 8; ++mt) {
        float4 pv = *(const float4*)&peb[perow * 128 + 16 * mt + 4 * quad];
        x[mt][0] = pc[mt][0] + pv.x; x[mt][1] = pc[mt][1] + pv.y;
        x[mt][2] = pc[mt][2] + pv.z; x[mt][3] = pc[mt][3] + pv.w;
        #pragma unroll
        for (int r = 0; r < 4; ++r) { sm += x[mt][r]; sq += x[mt][r] * x[mt][r]; }
    }
    sm += __shfl_xor(sm, 16); sq += __shfl_xor(sq, 16);
    sm += __shfl_xor(sm, 32); sq += __shfl_xor(sq, 32);
    float mean = sm * (1.0f / 128.0f);
    float var  = sq * (1.0f / 128.0f) - mean * mean;
    float rs   = rsqrtf(var + 1e-5f);
    #pragma unroll
    for (int mt = 0; mt < 8; ++mt) {
        float4 gv = *(const float4*)&s_g[16 * mt + 4 * quad];
        float4 bv = *(const float4*)&s_b[16 * mt + 4 * quad];
        float y0 = (x[mt][0] - mean) * rs * gv.x + bv.x;
        float y1 = (x[mt][1] - mean) * rs * gv.y + bv.y;
        float y2 = (x[mt][2] - mean) * rs * gv.z + bv.z;
        float y3 = (x[mt][3] - mean) * rs * gv.w + bv.w;
        unsigned long long w = ((unsigned long long)pack2(y2, y3) << 32) | pack2(y0, y1);
        *(unsigned long long*)&s_kb[rowkb * 132 + 16 * mt + 4 * quad] = w;
    }
}

// =====================================================================
// Kernel A: transposed-MFMA proj + in-reg LN + S^T flash attention.
// grid = 1024 (pair = bid>>1, half = bid&1), block = 256 (4 waves).
// LDS 54304 B -> 3 blocks/CU. 2 barriers per 64-key tile.
// =====================================================================
__global__ __launch_bounds__(256, 3)
void attn_kernel(const float* __restrict__ lookback,
                 const float* __restrict__ focal,
                 const float* __restrict__ Wp,
                 const float* __restrict__ peb,
                 const float* __restrict__ lng,
                 const float* __restrict__ lnb,
                 float* __restrict__ flat)
{
    __shared__ unsigned short s_sb0[SBLEN];     //  2592 B series bf16
    __shared__ unsigned short s_wpb[128 * 64];  // 16384 B Wp^T[e][d], XOR-swizzled blocks
    __shared__ unsigned short s_kb[64 * 132];   // 16896 B LN'd rows [row][e]
    __shared__ unsigned short s_P[128 * 68];    // 17408 B probs [qrow][key] (wave-local)
    __shared__ float s_g[DPD];                  //   512 B
    __shared__ float s_b[DPD];                  //   512 B

    const int t    = threadIdx.x;
    const int pair = blockIdx.x >> 1;
    const int hb   = blockIdx.x & 1;
    const int lane = t & 63;
    const int wave = t >> 6;
    const int quad = lane >> 4;
    const int kcol = lane & 15;

    // ---------------- init ----------------
    {
        if (t < 256) {
            float4 v = ((const float4*)(lookback + pair * LOOK))[t];
            s_sb0[4 * t]     = f2bu(v.x);
            s_sb0[4 * t + 1] = f2bu(v.y);
            s_sb0[4 * t + 2] = f2bu(v.z);
            s_sb0[4 * t + 3] = f2bu(v.w);
        }
        if (t < 64) {
            float4 v = ((const float4*)(focal + pair * PREDN))[t];
            s_sb0[LOOK + 4 * t]     = f2bu(v.x);
            s_sb0[LOOK + 4 * t + 1] = f2bu(v.y);
            s_sb0[LOOK + 4 * t + 2] = f2bu(v.z);
            s_sb0[LOOK + 4 * t + 3] = f2bu(v.w);
        }
        if (t < SBLEN - TOT) s_sb0[TOT + t] = 0;
        #pragma unroll
        for (int j = 0; j < 32; ++j) {            // Wp[k][e] -> swizzled Wp^T
            int fl = j * 256 + t;                 // coalesced
            int k = fl >> 7, e = fl & 127;
            s_wpb[e * 64 + (((k >> 3) ^ (e & 7)) << 3) + (k & 7)] = f2bu(Wp[fl]);
        }
        if (t < DPD) { s_g[t] = lng[t]; s_b[t] = lnb[t]; }
    }
    __syncthreads();

    // ---------------- q: 2 tiles of 64 rows ----------------
    short8 aq[2][4];   // wave's 32 q-rows as MFMA B-frags [ntQ][kc]
    for (int qt = 0; qt < 2; ++qt) {
        proj_tile(s_sb0, s_wpb, s_g, s_b, s_kb, peb,
                  972 + hb * RPB + 64 * qt + 16 * wave + kcol,
                  971 + hb * RPB + 64 * qt + 16 * wave + kcol,   // peb row <= 1220 < 1280
                  16 * wave + kcol, quad, kcol);
        __syncthreads();
        if ((wave >> 1) == qt) {
            #pragma unroll
            for (int ntQ = 0; ntQ < 2; ++ntQ) {
                int g = 2 * wave + ntQ - 4 * qt;   // row-in-tile group
                #pragma unroll
                for (int kc = 0; kc < 4; ++kc)
                    aq[ntQ][kc] = ld_b64x2(&s_kb[(16 * g + kcol) * 132 + 32 * kc + 8 * quad]);
            }
        }
        __syncthreads();
    }

    float mrow[2] = {-3.0e38f, -3.0e38f};
    float lrow[2] = {0.0f, 0.0f};
    f32x4 o[2][4];
    #pragma unroll
    for (int a = 0; a < 2; ++a)
        #pragma unroll
        for (int b = 0; b < 4; ++b) o[a][b] = (f32x4){0.f, 0.f, 0.f, 0.f};

    // ---------------- main loop: 16 tiles of 64 keys ----------------
    for (int tile = 0; tile < NKT; ++tile) {
        const int j0 = tile * 64;

        proj_tile(s_sb0, s_wpb, s_g, s_b, s_kb, peb,
                  j0 + 16 * wave + kcol, j0 + 16 * wave + kcol,
                  16 * wave + kcol, quad, kcol);
        __syncthreads();   // B1: k-tile ready

        // QK^T (S^T): D[key][qrow]; A = k rows, B = aq
        f32x4 sacc[2][4];
        #pragma unroll
        for (int a = 0; a < 2; ++a)
            #pragma unroll
            for (int b = 0; b < 4; ++b) sacc[a][b] = (f32x4){0.f, 0.f, 0.f, 0.f};
        #pragma unroll
        for (int kc = 0; kc < 4; ++kc) {
            short8 ak[4];
            #pragma unroll
            for (int mtK = 0; mtK < 4; ++mtK)
                ak[mtK] = ld_b64x2(&s_kb[(16 * mtK + kcol) * 132 + 32 * kc + 8 * quad]);
            #pragma unroll
            for (int ntQ = 0; ntQ < 2; ++ntQ)
                #pragma unroll
                for (int mtK = 0; mtK < 4; ++mtK)
                    sacc[ntQ][mtK] = __builtin_amdgcn_mfma_f32_16x16x32_bf16(
                        ak[mtK], aq[ntQ][kc], sacc[ntQ][mtK], 0, 0, 0);
        }

        // online softmax: per lane 2 q-rows (qrow = 16(2w+ntQ)+kcol), keys within-lane
        float alf[2];
        #pragma unroll
        for (int ntQ = 0; ntQ < 2; ++ntQ) {
            float P[4][4];
            float mx = -1.0e30f;
            #pragma unroll
            for (int mtK = 0; mtK < 4; ++mtK)
                #pragma unroll
                for (int r = 0; r < 4; ++r) {
                    int key = j0 + 16 * mtK + 4 * quad + r;
                    float s = (key < NK) ? sacc[ntQ][mtK][r] * SCALE : -1.0e30f;
                    P[mtK][r] = s;
                    mx = fmaxf(mx, s);
                }
            mx = fmaxf(mx, __shfl_xor(mx, 16));
            mx = fmaxf(mx, __shfl_xor(mx, 32));
            float mo = mrow[ntQ];
            float mn = fmaxf(mo, mx);
            float a  = __expf(mo - mn);
            float ss = 0.f;
            #pragma unroll
            for (int mtK = 0; mtK < 4; ++mtK)
                #pragma unroll
                for (int r = 0; r < 4; ++r) {
                    P[mtK][r] = __expf(P[mtK][r] - mn);
                    ss += P[mtK][r];
                }
            ss += __shfl_xor(ss, 16);
            ss += __shfl_xor(ss, 32);
            lrow[ntQ] = lrow[ntQ] * a + ss;
            mrow[ntQ] = mn;
            alf[ntQ]  = a;
            const int pbase = (16 * (2 * wave + ntQ) + kcol) * 68;
            #pragma unroll
            for (int mtK = 0; mtK < 4; ++mtK) {
                unsigned long long w = ((unsigned long long)pack2(P[mtK][2], P[mtK][3]) << 32)
                                       | pack2(P[mtK][0], P[mtK][1]);
                *(unsigned long long*)&s_P[pbase + 16 * mtK + 4 * quad] = w;
            }
        }

        // rescale O by alpha (state lane -> accumulator lane via shuffle)
        #pragma unroll
        for (int ntQ = 0; ntQ < 2; ++ntQ)
            #pragma unroll
            for (int r = 0; r < 4; ++r) {
                float af = __shfl(alf[ntQ], 20 * quad + r);
                #pragma unroll
                for (int ntD = 0; ntD < 4; ++ntD) o[ntQ][ntD][r] *= af;
            }

        // PV: A = P (s_P, wave-local), B = X^T straight from series
        short8 xf[4][2];
        #pragma unroll
        for (int ntD = 0; ntD < 4; ++ntD)
            #pragma unroll
            for (int kc2 = 0; kc2 < 2; ++kc2)
                xf[ntD][kc2] = load_sfrag(s_sb0, j0 + 1 + 32 * kc2 + 8 * quad + 16 * ntD + kcol);
        #pragma unroll
        for (int ntQ = 0; ntQ < 2; ++ntQ) {
            const int pbase = (16 * (2 * wave + ntQ) + kcol) * 68;
            short8 ap[2];
            #pragma unroll
            for (int kc2 = 0; kc2 < 2; ++kc2)
                ap[kc2] = ld_b64x2(&s_P[pbase + 32 * kc2 + 8 * quad]);
            #pragma unroll
            for (int ntD = 0; ntD < 4; ++ntD)
                #pragma unroll
                for (int kc2 = 0; kc2 < 2; ++kc2)
                    o[ntQ][ntD] = __builtin_amdgcn_mfma_f32_16x16x32_bf16(
                        ap[kc2], xf[ntD][kc2], o[ntQ][ntD], 0, 0, 0);
        }
        __syncthreads();   // B2: s_kb free for next tile's proj
    }

    // ---------------- epilogue ----------------
    float inv[2] = {1.0f / lrow[0], 1.0f / lrow[1]};
    #pragma unroll
    for (int ntQ = 0; ntQ < 2; ++ntQ)
        #pragma unroll
        for (int r = 0; r < 4; ++r) {
            float li = __shfl(inv[ntQ], 20 * quad + r);
            int brow = 32 * wave + 16 * ntQ + 4 * quad + r;
            if (brow < RPB) {
                float* dst = flat + pair * 15616 + (hb * RPB + brow) * 64 + kcol;
                #pragma unroll
                for (int ntD = 0; ntD < 4; ++ntD)
                    dst[16 * ntD] = o[ntQ][ntD][r] * li;
            }
        }
}

// =====================================================================
// Kernel P: peb = pe + bp (folded bias), 1280x128.
// =====================================================================
__global__ void peb_kernel(const float* __restrict__ pe,
                           const float* __restrict__ bp,
                           float* __restrict__ peb)
{
    int i = blockIdx.x * 256 + threadIdx.x;   // 163840
    peb[i] = pe[i] + bp[i & 127];
}

// =====================================================================
// Kernel B: flat(512x15616) @ W1(15616x256) -> split-K partials.
// =====================================================================
__global__ __launch_bounds__(256, 2)
void mlp1_kernel(const float* __restrict__ flat,
                 const float* __restrict__ W1,
                 float* __restrict__ part)
{
    const int bid = blockIdx.x;
    const int bm = bid & 7, bn = (bid >> 3) & 3, bz = bid >> 5;
    const int m0 = bm * 64, n0 = bn * 64;
    const int t0 = bz * 30 + (bz < 8 ? bz : 8);   // 488 k-tiles of 32 total
    const int nt = (bz < 8) ? 31 : 30;

    __shared__ float sA[64 * 36];
    __shared__ float sB[32 * 68];
    float acc[16];
    #pragma unroll
    for (int i = 0; i < 16; ++i) acc[i] = 0.0f;

    const int wv = threadIdx.x >> 6, ln = threadIdx.x & 63;
    const int tm = 4 * wv + (ln >> 4), tn = ln & 15;
    const int r = threadIdx.x >> 3;
    const int c4 = (threadIdx.x & 7) * 4;
    const int c8 = (threadIdx.x & 7) * 8;

    for (int tt = 0; tt < nt; ++tt) {
        const int kc = (t0 + tt) * 32;
        *(float4*)&sA[r * 36 + c4]        = *(const float4*)(flat + (m0 + r) * 15616 + kc + c4);
        *(float4*)&sA[(r + 32) * 36 + c4] = *(const float4*)(flat + (m0 + r + 32) * 15616 + kc + c4);
        *(float4*)&sB[r * 68 + c8]     = *(const float4*)(W1 + (kc + r) * 256 + n0 + c8);
        *(float4*)&sB[r * 68 + c8 + 4] = *(const float4*)(W1 + (kc + r) * 256 + n0 + c8 + 4);
        __syncthreads();
        #pragma unroll
        for (int kg = 0; kg < 8; ++kg) {
            float4 a[4], b[4];
            #pragma unroll
            for (int i = 0; i < 4; ++i) a[i] = *(const float4*)&sA[(4 * tm + i) * 36 + 4 * kg];
            #pragma unroll
            for (int j = 0; j < 4; ++j) b[j] = *(const float4*)&sB[(4 * kg + j) * 68 + 4 * tn];
            #pragma unroll
            for (int i = 0; i < 4; ++i) {
                acc[4*i+0] += a[i].x*b[0].x + a[i].y*b[1].x + a[i].z*b[2].x + a[i].w*b[3].x;
                acc[4*i+1] += a[i].x*b[0].y + a[i].y*b[1].y + a[i].z*b[2].y + a[i].w*b[3].y;
                acc[4*i+2] += a[i].x*b[0].z + a[i].y*b[1].z + a[i].z*b[2].z + a[i].w*b[3].z;
                acc[4*i+3] += a[i].x*b[0].w + a[i].y*b[1].w + a[i].z*b[2].w + a[i].w*b[3].w;
            }
        }
        __syncthreads();
    }
    float* dst = part + bz * (512 * 256);
    #pragma unroll
    for (int i = 0; i < 4; ++i)
        *(float4*)&dst[(m0 + 4 * tm + i) * 256 + n0 + 4 * tn] =
            make_float4(acc[4*i+0], acc[4*i+1], acc[4*i+2], acc[4*i+3]);
}

// =====================================================================
// Kernel C: reduce 16 partials + bias + exact GELU -> H (512x256).
// =====================================================================
__global__ void gelu_kernel(const float* __restrict__ part,
                            const float* __restrict__ b1,
                            float* __restrict__ H)
{
    const int i = blockIdx.x * 256 + threadIdx.x;
    float s = 0.0f;
    #pragma unroll
    for (int ks = 0; ks < 16; ++ks) s += part[ks * 131072 + i];
    s += b1[i & 255];
    H[i] = 0.5f * s * (1.0f + erff(s * 0.7071067811865475f));
}

// =====================================================================
// Kernel D: out = H(512x256) @ W2(256x256) + b2 (fp32 out).
// =====================================================================
__global__ __launch_bounds__(256, 2)
void mlp2_kernel(const float* __restrict__ H,
                 const float* __restrict__ W2,
                 const float* __restrict__ b2,
                 float* __restrict__ out)
{
    const int bm = blockIdx.x & 7, bn = blockIdx.x >> 3;
    const int m0 = bm * 64, n0 = bn * 64;
    __shared__ float sA[64 * 36];
    __shared__ float sB[32 * 68];
    float acc[16];
    #pragma unroll
    for (int i = 0; i < 16; ++i) acc[i] = 0.0f;

    const int wv = threadIdx.x >> 6, ln = threadIdx.x & 63;
    const int tm = 4 * wv + (ln >> 4), tn = ln & 15;
    const int r = threadIdx.x >> 3;
    const int c4 = (threadIdx.x & 7) * 4;
    const int c8 = (threadIdx.x & 7) * 8;

    for (int tt = 0; tt < 8; ++tt) {
        const int kc = tt * 32;
        *(float4*)&sA[r * 36 + c4]        = *(const float4*)(H + (m0 + r) * 256 + kc + c4);
        *(float4*)&sA[(r + 32) * 36 + c4] = *(const float4*)(H + (m0 + r + 32) * 256 + kc + c4);
        *(float4*)&sB[r * 68 + c8]     = *(const float4*)(W2 + (kc + r) * 256 + n0 + c8);
        *(float4*)&sB[r * 68 + c8 + 4] = *(const float4*)(W2 + (kc + r) * 256 + n0 + c8 + 4);
        __syncthreads();
        #pragma unroll
        for (int kg = 0; kg < 8; ++kg) {
            float4 a[4], b[4];
            #pragma unroll
            for (int i = 0; i < 4; ++i) a[i] = *(const float4*)&sA[(4 * tm + i) * 36 + 4 * kg];
            #pragma unroll
            for (int j = 0; j < 4; ++j) b[j] = *(const float4*)&sB[(4 * kg + j) * 68 + 4 * tn];
            #pragma unroll
            for (int i = 0; i < 4; ++i) {
                acc[4*i+0] += a[i].x*b[0].x + a[i].y*b[1].x + a[i].z*b[2].x + a[i].w*b[3].x;
                acc[4*i+1] += a[i].x*b[0].y + a[i].y*b[1].y + a[i].z*b[2].y + a[i].w*b[3].y;
                acc[4*i+2] += a[i].x*b[0].z + a[i].y*b[1].z + a[i].z*b[2].z + a[i].w*b[3].z;
                acc[4*i+3] += a[i].x*b[0].w + a[i].y*b[1].w + a[i].z*b[2].w + a[i].w*b[3].w;
            }
        }
        __syncthreads();
    }
    #pragma unroll
    for (int i = 0; i < 4; ++i)
        #pragma unroll
        for (int j = 0; j < 4; ++j) {
            const int m = m0 + 4 * tm + i, n = n0 + 4 * tn + j;
            out[m * 256 + n] = acc[4 * i + j] + b2[n];
        }
}

extern "C" void kernel_launch(void* const* d_in, const int* in_sizes, int n_in,
                              void* d_out, int out_size, void* d_ws, size_t ws_size,
                              hipStream_t stream) {
    (void)in_sizes; (void)n_in; (void)out_size; (void)ws_size;
    const float* lookback = (const float*)d_in[0];
    const float* focal    = (const float*)d_in[1];
    const float* Wp       = (const float*)d_in[2];
    const float* bp       = (const float*)d_in[3];
    const float* pe       = (const float*)d_in[4];
    const float* lng      = (const float*)d_in[5];
    const float* lnb      = (const float*)d_in[6];
    const float* W1       = (const float*)d_in[7];
    const float* b1       = (const float*)d_in[8];
    const float* W2       = (const float*)d_in[9];
    const float* b2       = (const float*)d_in[10];

    float* flat = (float*)d_ws;                   // 512*15616 floats (32 MB)
    float* part = flat + 512 * 15616;             // 16*512*256 floats (8 MB)
    float* H    = part + 16 * 512 * 256;          // 512*256 floats
    float* peb  = part;                           // alias: peb used only by attn,
                                                  // part written by mlp1 afterwards

    hipLaunchKernelGGL(peb_kernel, dim3(640), dim3(256), 0, stream, pe, bp, peb);
    hipLaunchKernelGGL(attn_kernel, dim3(1024), dim3(256), 0, stream,
                       lookback, focal, Wp, peb, lng, lnb, flat);
    hipLaunchKernelGGL(mlp1_kernel, dim3(512), dim3(256), 0, stream, flat, W1, part);
    hipLaunchKernelGGL(gelu_kernel, dim3(512), dim3(256), 0, stream, part, b1, H);
    hipLaunchKernelGGL(mlp2_kernel, dim3(32), dim3(256), 0, stream, H, W2, b2,
                       (float*)d_out);
}

// Round 10
// 323.156 us; speedup vs baseline: 5.2483x; 1.1086x over previous
//
#include <hip/hip_runtime.h>
#include <hip/hip_bf16.h>

#define LOOK   1024
#define PREDN  256
#define TOT    1280
#define SBLEN  1296       // bf16 series + zero tail (max read elem 1285)
#define DPD    128
#define NK     971        // number of keys (T)
#define RPB    122        // valid q-rows per block (2 blocks/pair)
#define NKT    16         // 16 key-tiles of 64 (1024 >= 971)
#define SCALE  0.08838834764831845f  // 1/sqrt(128)

typedef __attribute__((ext_vector_type(8))) short short8;
typedef __attribute__((ext_vector_type(4))) float f32x4;

__device__ __forceinline__ unsigned short f2bu(float x) {
    union { __hip_bfloat16 b; unsigned short u; } v;
    v.b = __float2bfloat16(x);
    return v.u;
}
__device__ __forceinline__ unsigned int pack2(float a, float b) {
    return (unsigned int)f2bu(a) | ((unsigned int)f2bu(b) << 16);
}

// 8 contiguous bf16 from series at element idx0 (any parity): 5 dwords + funnel shift.
__device__ __forceinline__ short8 load_sfrag(const unsigned short* s0, int idx0) {
    const unsigned int* p = (const unsigned int*)s0 + (idx0 >> 1);
    const unsigned int sh = (idx0 & 1) << 4;
    unsigned int w0 = p[0], w1 = p[1], w2 = p[2], w3 = p[3], w4 = p[4];
    union { unsigned int u[4]; short8 s; } v;
    v.u[0] = (unsigned int)((((unsigned long long)w1 << 32) | w0) >> sh);
    v.u[1] = (unsigned int)((((unsigned long long)w2 << 32) | w1) >> sh);
    v.u[2] = (unsigned int)((((unsigned long long)w3 << 32) | w2) >> sh);
    v.u[3] = (unsigned int)((((unsigned long long)w4 << 32) | w3) >> sh);
    return v.s;
}
// 8 bf16 from LDS at 8B-aligned (not 16B) address: two b64 reads.
__device__ __forceinline__ short8 ld_b64x2(const unsigned short* p) {
    union { unsigned long long q[2]; short8 s; } v;
    v.q[0] = *(const unsigned long long*)p;
    v.q[1] = *(const unsigned long long*)(p + 4);
    return v.s;
}

// Fused projection of 64 rows (16 per wave) + pe' + in-register LN -> s_kb[row][e].
__device__ __forceinline__ void proj_tile(
    const unsigned short* s_sb0, const unsigned short* s_wpb,
    const unsigned int* s_gb, unsigned short* s_kb,
    const float* __restrict__ peb,
    int widx, int perow, int rowkb, int quad, int kcol)
{
    short8 bw0 = load_sfrag(s_sb0, widx + 8 * quad);
    short8 bw1 = load_sfrag(s_sb0, widx + 32 + 8 * quad);
    f32x4 pc[8];
    #pragma unroll
    for (int mt = 0; mt < 8; ++mt) pc[mt] = (f32x4){0.f, 0.f, 0.f, 0.f};
    const int k7 = kcol & 7;
    #pragma unroll
    for (int mt = 0; mt < 8; ++mt) {
        int e = 16 * mt + kcol;
        short8 a0 = *(const short8*)&s_wpb[e * 64 + ((quad ^ k7) << 3)];
        short8 a1 = *(const short8*)&s_wpb[e * 64 + (((4 + quad) ^ k7) << 3)];
        pc[mt] = __builtin_amdgcn_mfma_f32_16x16x32_bf16(a0, bw0, pc[mt], 0, 0, 0);
        pc[mt] = __builtin_amdgcn_mfma_f32_16x16x32_bf16(a1, bw1, pc[mt], 0, 0, 0);
    }
    float x[8][4];
    float sm = 0.f, sq = 0.f;
    #pragma unroll
    for (int mt = 0; mt < 8; ++mt) {
        float4 pv = *(const float4*)&peb[perow * 128 + 16 * mt + 4 * quad];
        x[mt][0] = pc[mt][0] + pv.x; x[mt][1] = pc[mt][1] + pv.y;
        x[mt][2] = pc[mt][2] + pv.z; x[mt][3] = pc[mt][3] + pv.w;
        #pragma unroll
        for (int r = 0; r < 4; ++r) { sm += x[mt][r]; sq += x[mt][r] * x[mt][r]; }
    }
    sm += __shfl_xor(sm, 16); sq += __shfl_xor(sq, 16);
    sm += __shfl_xor(sm, 32); sq += __shfl_xor(sq, 32);
    float mean = sm * (1.0f / 128.0f);
    float var  = sq * (1.0f / 128.0f) - mean * mean;
    float rs   = rsqrtf(var + 1e-5f);
    #pragma unroll
    for (int mt = 0; mt < 8; ++mt) {
        uint4 gb = *(const uint4*)&s_gb[16 * mt + 4 * quad];
        unsigned int gw[4] = {gb.x, gb.y, gb.z, gb.w};
        float y[4];
        #pragma unroll
        for (int r = 0; r < 4; ++r) {
            float g = __uint_as_float(gw[r] << 16);
            float b = __uint_as_float(gw[r] & 0xFFFF0000u);
            y[r] = (x[mt][r] - mean) * rs * g + b;
        }
        unsigned long long w = ((unsigned long long)pack2(y[2], y[3]) << 32) | pack2(y[0], y[1]);
        *(unsigned long long*)&s_kb[rowkb * 132 + 16 * mt + 4 * quad] = w;
    }
}

// =====================================================================
// Kernel A: transposed-MFMA proj + in-reg LN + S^T flash attention.
// grid = 1024 (pair = bid>>1, half = bid&1), block = 256 (4 waves).
// LDS 53792 B -> rounds to 54272 -> 3 blocks/CU.
// Epilogue emits flat as bf16 hi + lo residual for the MFMA mlp1.
// =====================================================================
__global__ __launch_bounds__(256, 3)
void attn_kernel(const float* __restrict__ lookback,
                 const float* __restrict__ focal,
                 const float* __restrict__ Wp,
                 const float* __restrict__ peb,
                 const float* __restrict__ lng,
                 const float* __restrict__ lnb,
                 unsigned short* __restrict__ flat_hi,
                 unsigned short* __restrict__ flat_lo)
{
    __shared__ unsigned short s_sb0[SBLEN];     //  2592 B series bf16
    __shared__ unsigned short s_wpb[128 * 64];  // 16384 B Wp^T[e][d], XOR-swizzled
    __shared__ unsigned short s_kb[64 * 132];   // 16896 B LN'd rows [row][e]
    __shared__ unsigned short s_P[128 * 68];    // 17408 B probs [qrow][key]
    __shared__ unsigned int   s_gb[DPD];        //   512 B (g lo16, b hi16)

    const int t    = threadIdx.x;
    const int pair = blockIdx.x >> 1;
    const int hb   = blockIdx.x & 1;
    const int lane = t & 63;
    const int wave = t >> 6;
    const int quad = lane >> 4;
    const int kcol = lane & 15;

    // ---------------- init ----------------
    {
        if (t < 256) {
            float4 v = ((const float4*)(lookback + pair * LOOK))[t];
            s_sb0[4 * t]     = f2bu(v.x);
            s_sb0[4 * t + 1] = f2bu(v.y);
            s_sb0[4 * t + 2] = f2bu(v.z);
            s_sb0[4 * t + 3] = f2bu(v.w);
        }
        if (t < 64) {
            float4 v = ((const float4*)(focal + pair * PREDN))[t];
            s_sb0[LOOK + 4 * t]     = f2bu(v.x);
            s_sb0[LOOK + 4 * t + 1] = f2bu(v.y);
            s_sb0[LOOK + 4 * t + 2] = f2bu(v.z);
            s_sb0[LOOK + 4 * t + 3] = f2bu(v.w);
        }
        if (t < SBLEN - TOT) s_sb0[TOT + t] = 0;
        #pragma unroll
        for (int j = 0; j < 32; ++j) {            // Wp[k][e] -> swizzled Wp^T
            int fl = j * 256 + t;
            int k = fl >> 7, e = fl & 127;
            s_wpb[e * 64 + (((k >> 3) ^ (e & 7)) << 3) + (k & 7)] = f2bu(Wp[fl]);
        }
        if (t < DPD)
            s_gb[t] = (unsigned int)f2bu(lng[t]) | ((unsigned int)f2bu(lnb[t]) << 16);
    }
    __syncthreads();

    // ---------------- q: 2 tiles of 64 rows ----------------
    short8 aq[2][4];
    for (int qt = 0; qt < 2; ++qt) {
        proj_tile(s_sb0, s_wpb, s_gb, s_kb, peb,
                  972 + hb * RPB + 64 * qt + 16 * wave + kcol,
                  971 + hb * RPB + 64 * qt + 16 * wave + kcol,
                  16 * wave + kcol, quad, kcol);
        __syncthreads();
        if ((wave >> 1) == qt) {
            #pragma unroll
            for (int ntQ = 0; ntQ < 2; ++ntQ) {
                int g = 2 * wave + ntQ - 4 * qt;
                #pragma unroll
                for (int kc = 0; kc < 4; ++kc)
                    aq[ntQ][kc] = ld_b64x2(&s_kb[(16 * g + kcol) * 132 + 32 * kc + 8 * quad]);
            }
        }
        __syncthreads();
    }

    float mrow[2] = {-3.0e38f, -3.0e38f};
    float lrow[2] = {0.0f, 0.0f};
    f32x4 o[2][4];
    #pragma unroll
    for (int a = 0; a < 2; ++a)
        #pragma unroll
        for (int b = 0; b < 4; ++b) o[a][b] = (f32x4){0.f, 0.f, 0.f, 0.f};

    // ---------------- main loop: 16 tiles of 64 keys ----------------
    for (int tile = 0; tile < NKT; ++tile) {
        const int j0 = tile * 64;

        proj_tile(s_sb0, s_wpb, s_gb, s_kb, peb,
                  j0 + 16 * wave + kcol, j0 + 16 * wave + kcol,
                  16 * wave + kcol, quad, kcol);
        __syncthreads();   // B1: k-tile ready

        f32x4 sacc[2][4];
        #pragma unroll
        for (int a = 0; a < 2; ++a)
            #pragma unroll
            for (int b = 0; b < 4; ++b) sacc[a][b] = (f32x4){0.f, 0.f, 0.f, 0.f};
        #pragma unroll
        for (int kc = 0; kc < 4; ++kc) {
            short8 ak[4];
            #pragma unroll
            for (int mtK = 0; mtK < 4; ++mtK)
                ak[mtK] = ld_b64x2(&s_kb[(16 * mtK + kcol) * 132 + 32 * kc + 8 * quad]);
            #pragma unroll
            for (int ntQ = 0; ntQ < 2; ++ntQ)
                #pragma unroll
                for (int mtK = 0; mtK < 4; ++mtK)
                    sacc[ntQ][mtK] = __builtin_amdgcn_mfma_f32_16x16x32_bf16(
                        ak[mtK], aq[ntQ][kc], sacc[ntQ][mtK], 0, 0, 0);
        }

        float alf[2];
        #pragma unroll
        for (int ntQ = 0; ntQ < 2; ++ntQ) {
            float P[4][4];
            float mx = -1.0e30f;
            #pragma unroll
            for (int mtK = 0; mtK < 4; ++mtK)
                #pragma unroll
                for (int r = 0; r < 4; ++r) {
                    int key = j0 + 16 * mtK + 4 * quad + r;
                    float s = (key < NK) ? sacc[ntQ][mtK][r] * SCALE : -1.0e30f;
                    P[mtK][r] = s;
                    mx = fmaxf(mx, s);
                }
            mx = fmaxf(mx, __shfl_xor(mx, 16));
            mx = fmaxf(mx, __shfl_xor(mx, 32));
            float mo = mrow[ntQ];
            float mn = fmaxf(mo, mx);
            float a  = __expf(mo - mn);
            float ss = 0.f;
            #pragma unroll
            for (int mtK = 0; mtK < 4; ++mtK)
                #pragma unroll
                for (int r = 0; r < 4; ++r) {
                    P[mtK][r] = __expf(P[mtK][r] - mn);
                    ss += P[mtK][r];
                }
            ss += __shfl_xor(ss, 16);
            ss += __shfl_xor(ss, 32);
            lrow[ntQ] = lrow[ntQ] * a + ss;
            mrow[ntQ] = mn;
            alf[ntQ]  = a;
            const int pbase = (16 * (2 * wave + ntQ) + kcol) * 68;
            #pragma unroll
            for (int mtK = 0; mtK < 4; ++mtK) {
                unsigned long long w = ((unsigned long long)pack2(P[mtK][2], P[mtK][3]) << 32)
                                       | pack2(P[mtK][0], P[mtK][1]);
                *(unsigned long long*)&s_P[pbase + 16 * mtK + 4 * quad] = w;
            }
        }

        #pragma unroll
        for (int ntQ = 0; ntQ < 2; ++ntQ)
            #pragma unroll
            for (int r = 0; r < 4; ++r) {
                float af = __shfl(alf[ntQ], 20 * quad + r);
                #pragma unroll
                for (int ntD = 0; ntD < 4; ++ntD) o[ntQ][ntD][r] *= af;
            }

        short8 xf[4][2];
        #pragma unroll
        for (int ntD = 0; ntD < 4; ++ntD)
            #pragma unroll
            for (int kc2 = 0; kc2 < 2; ++kc2)
                xf[ntD][kc2] = load_sfrag(s_sb0, j0 + 1 + 32 * kc2 + 8 * quad + 16 * ntD + kcol);
        #pragma unroll
        for (int ntQ = 0; ntQ < 2; ++ntQ) {
            const int pbase = (16 * (2 * wave + ntQ) + kcol) * 68;
            short8 ap[2];
            #pragma unroll
            for (int kc2 = 0; kc2 < 2; ++kc2)
                ap[kc2] = ld_b64x2(&s_P[pbase + 32 * kc2 + 8 * quad]);
            #pragma unroll
            for (int ntD = 0; ntD < 4; ++ntD)
                #pragma unroll
                for (int kc2 = 0; kc2 < 2; ++kc2)
                    o[ntQ][ntD] = __builtin_amdgcn_mfma_f32_16x16x32_bf16(
                        ap[kc2], xf[ntD][kc2], o[ntQ][ntD], 0, 0, 0);
        }
        __syncthreads();   // B2: s_kb free for next tile
    }

    // ---------------- epilogue: hi/lo bf16 split store ----------------
    float inv[2] = {1.0f / lrow[0], 1.0f / lrow[1]};
    #pragma unroll
    for (int ntQ = 0; ntQ < 2; ++ntQ)
        #pragma unroll
        for (int r = 0; r < 4; ++r) {
            float li = __shfl(inv[ntQ], 20 * quad + r);
            int brow = 32 * wave + 16 * ntQ + 4 * quad + r;
            if (brow < RPB) {
                int base = pair * 15616 + (hb * RPB + brow) * 64 + kcol;
                #pragma unroll
                for (int ntD = 0; ntD < 4; ++ntD) {
                    float v = o[ntQ][ntD][r] * li;
                    unsigned short h = f2bu(v);
                    float vh = __uint_as_float((unsigned int)h << 16);
                    flat_hi[base + 16 * ntD] = h;
                    flat_lo[base + 16 * ntD] = f2bu(v - vh);
                }
            }
        }
}

// =====================================================================
// Kernel P: peb = pe + bp (folded bias), 1280x128.
// =====================================================================
__global__ void peb_kernel(const float* __restrict__ pe,
                           const float* __restrict__ bp,
                           float* __restrict__ peb)
{
    int i = blockIdx.x * 256 + threadIdx.x;   // 163840
    peb[i] = pe[i] + bp[i & 127];
}

// =====================================================================
// Kernel B: mlp1 = flat(512x15616) @ W1(15616x256), bf16 MFMA hi/lo
// 3-pass (Ah*Bh + Al*Bh + Ah*Bl). grid = 512 (8m x 4n x 16 k-splits).
// W1 transposed on the fly into LDS (u16 scatter, stride-44 pad).
// =====================================================================
__global__ __launch_bounds__(256, 2)
void mlp1_kernel(const unsigned short* __restrict__ Ah,
                 const unsigned short* __restrict__ Al,
                 const float* __restrict__ W1,
                 float* __restrict__ part)
{
    const int bid = blockIdx.x;
    const int bm = bid & 7, bn = (bid >> 3) & 3, bz = bid >> 5;
    const int m0 = bm * 64, n0 = bn * 64;
    const int t0 = bz * 30 + (bz < 8 ? bz : 8);   // 488 k-tiles of 32 total
    const int nt = (bz < 8) ? 31 : 30;

    __shared__ unsigned short sAh[64 * 40];   // [m][k], pad 8
    __shared__ unsigned short sAl[64 * 40];
    __shared__ unsigned short sBh[64 * 44];   // [n][k] (W1^T), pad 12
    __shared__ unsigned short sBl[64 * 44];

    const int t = threadIdx.x;
    const int wv = t >> 6, lane = t & 63;
    const int quad = lane >> 4, kcol = lane & 15;
    const int ar = t >> 2, ac8 = (t & 3) * 8;     // A staging: 64 rows x 32 k
    const int bk = t >> 3, bn8 = (t & 7) * 8;     // B staging: 32 k x 64 n

    f32x4 acc[4];
    #pragma unroll
    for (int i = 0; i < 4; ++i) acc[i] = (f32x4){0.f, 0.f, 0.f, 0.f};

    for (int tt = 0; tt < nt; ++tt) {
        const int kc = (t0 + tt) * 32;
        // A tiles: 16B vector copies (bf16 row-major, aligned)
        *(uint4*)&sAh[ar * 40 + ac8] = *(const uint4*)(Ah + (m0 + ar) * 15616 + kc + ac8);
        *(uint4*)&sAl[ar * 40 + ac8] = *(const uint4*)(Al + (m0 + ar) * 15616 + kc + ac8);
        // B tile: read W1 fp32, split hi/lo, transpose-scatter into LDS
        {
            const float* wp = W1 + (kc + bk) * 256 + n0 + bn8;
            float4 wa = *(const float4*)wp;
            float4 wb = *(const float4*)(wp + 4);
            float vv[8] = {wa.x, wa.y, wa.z, wa.w, wb.x, wb.y, wb.z, wb.w};
            #pragma unroll
            for (int i = 0; i < 8; ++i) {
                unsigned short h = f2bu(vv[i]);
                float vh = __uint_as_float((unsigned int)h << 16);
                sBh[(bn8 + i) * 44 + bk] = h;
                sBl[(bn8 + i) * 44 + bk] = f2bu(vv[i] - vh);
            }
        }
        __syncthreads();
        short8 bh = ld_b64x2(&sBh[(16 * wv + kcol) * 44 + quad * 8]);
        short8 bl = ld_b64x2(&sBl[(16 * wv + kcol) * 44 + quad * 8]);
        #pragma unroll
        for (int mt = 0; mt < 4; ++mt) {
            short8 ah = *(const short8*)&sAh[(16 * mt + kcol) * 40 + quad * 8];
            short8 al = *(const short8*)&sAl[(16 * mt + kcol) * 40 + quad * 8];
            acc[mt] = __builtin_amdgcn_mfma_f32_16x16x32_bf16(ah, bh, acc[mt], 0, 0, 0);
            acc[mt] = __builtin_amdgcn_mfma_f32_16x16x32_bf16(al, bh, acc[mt], 0, 0, 0);
            acc[mt] = __builtin_amdgcn_mfma_f32_16x16x32_bf16(ah, bl, acc[mt], 0, 0, 0);
        }
        __syncthreads();
    }
    float* dst = part + bz * (512 * 256);
    #pragma unroll
    for (int mt = 0; mt < 4; ++mt)
        #pragma unroll
        for (int r = 0; r < 4; ++r)
            dst[(m0 + 16 * mt + 4 * quad + r) * 256 + n0 + 16 * wv + kcol] = acc[mt][r];
}

// =====================================================================
// Kernel C: reduce 16 partials + bias + exact GELU -> H (512x256).
// =====================================================================
__global__ void gelu_kernel(const float* __restrict__ part,
                            const float* __restrict__ b1,
                            float* __restrict__ H)
{
    const int i = blockIdx.x * 256 + threadIdx.x;
    float s = 0.0f;
    #pragma unroll
    for (int ks = 0; ks < 16; ++ks) s += part[ks * 131072 + i];
    s += b1[i & 255];
    H[i] = 0.5f * s * (1.0f + erff(s * 0.7071067811865475f));
}

// =====================================================================
// Kernel D: out = H(512x256) @ W2(256x256) + b2 (fp32 out).
// =====================================================================
__global__ __launch_bounds__(256, 2)
void mlp2_kernel(const float* __restrict__ H,
                 const float* __restrict__ W2,
                 const float* __restrict__ b2,
                 float* __restrict__ out)
{
    const int bm = blockIdx.x & 7, bn = blockIdx.x >> 3;
    const int m0 = bm * 64, n0 = bn * 64;
    __shared__ float sA[64 * 36];
    __shared__ float sB[32 * 68];
    float acc[16];
    #pragma unroll
    for (int i = 0; i < 16; ++i) acc[i] = 0.0f;

    const int wv = threadIdx.x >> 6, ln = threadIdx.x & 63;
    const int tm = 4 * wv + (ln >> 4), tn = ln & 15;
    const int r = threadIdx.x >> 3;
    const int c4 = (threadIdx.x & 7) * 4;
    const int c8 = (threadIdx.x & 7) * 8;

    for (int tt = 0; tt < 8; ++tt) {
        const int kc = tt * 32;
        *(float4*)&sA[r * 36 + c4]        = *(const float4*)(H + (m0 + r) * 256 + kc + c4);
        *(float4*)&sA[(r + 32) * 36 + c4] = *(const float4*)(H + (m0 + r + 32) * 256 + kc + c4);
        *(float4*)&sB[r * 68 + c8]     = *(const float4*)(W2 + (kc + r) * 256 + n0 + c8);
        *(float4*)&sB[r * 68 + c8 + 4] = *(const float4*)(W2 + (kc + r) * 256 + n0 + c8 + 4);
        __syncthreads();
        #pragma unroll
        for (int kg = 0; kg < 8; ++kg) {
            float4 a[4], b[4];
            #pragma unroll
            for (int i = 0; i < 4; ++i) a[i] = *(const float4*)&sA[(4 * tm + i) * 36 + 4 * kg];
            #pragma unroll
            for (int j = 0; j < 4; ++j) b[j] = *(const float4*)&sB[(4 * kg + j) * 68 + 4 * tn];
            #pragma unroll
            for (int i = 0; i < 4; ++i) {
                acc[4*i+0] += a[i].x*b[0].x + a[i].y*b[1].x + a[i].z*b[2].x + a[i].w*b[3].x;
                acc[4*i+1] += a[i].x*b[0].y + a[i].y*b[1].y + a[i].z*b[2].y + a[i].w*b[3].y;
                acc[4*i+2] += a[i].x*b[0].z + a[i].y*b[1].z + a[i].z*b[2].z + a[i].w*b[3].z;
                acc[4*i+3] += a[i].x*b[0].w + a[i].y*b[1].w + a[i].z*b[2].w + a[i].w*b[3].w;
            }
        }
        __syncthreads();
    }
    #pragma unroll
    for (int i = 0; i < 4; ++i)
        #pragma unroll
        for (int j = 0; j < 4; ++j) {
            const int m = m0 + 4 * tm + i, n = n0 + 4 * tn + j;
            out[m * 256 + n] = acc[4 * i + j] + b2[n];
        }
}

extern "C" void kernel_launch(void* const* d_in, const int* in_sizes, int n_in,
                              void* d_out, int out_size, void* d_ws, size_t ws_size,
                              hipStream_t stream) {
    (void)in_sizes; (void)n_in; (void)out_size; (void)ws_size;
    const float* lookback = (const float*)d_in[0];
    const float* focal    = (const float*)d_in[1];
    const float* Wp       = (const float*)d_in[2];
    const float* bp       = (const float*)d_in[3];
    const float* pe       = (const float*)d_in[4];
    const float* lng      = (const float*)d_in[5];
    const float* lnb      = (const float*)d_in[6];
    const float* W1       = (const float*)d_in[7];
    const float* b1       = (const float*)d_in[8];
    const float* W2       = (const float*)d_in[9];
    const float* b2       = (const float*)d_in[10];

    unsigned short* flat_hi = (unsigned short*)d_ws;        // 512*15616 bf16 (16 MB)
    unsigned short* flat_lo = flat_hi + 512 * 15616;        // 16 MB
    float* part = (float*)(flat_lo + 512 * 15616);          // 16*512*256 f32 (8 MB)
    float* H    = part + 16 * 512 * 256;                    // 0.5 MB
    float* peb  = part;   // alias: read by attn, overwritten later by mlp1

    hipLaunchKernelGGL(peb_kernel, dim3(640), dim3(256), 0, stream, pe, bp, peb);
    hipLaunchKernelGGL(attn_kernel, dim3(1024), dim3(256), 0, stream,
                       lookback, focal, Wp, peb, lng, lnb, flat_hi, flat_lo);
    hipLaunchKernelGGL(mlp1_kernel, dim3(512), dim3(256), 0, stream,
                       flat_hi, flat_lo, W1, part);
    hipLaunchKernelGGL(gelu_kernel, dim3(512), dim3(256), 0, stream, part, b1, H);
    hipLaunchKernelGGL(mlp2_kernel, dim3(32), dim3(256), 0, stream, H, W2, b2,
                       (float*)d_out);
}

// Round 11
// 281.498 us; speedup vs baseline: 6.0250x; 1.1480x over previous
//
#include <hip/hip_runtime.h>
#include <hip/hip_bf16.h>

#define LOOK   1024
#define PREDN  256
#define TOT    1280
#define SBLEN  1296       // bf16 series + zero tail (max read elem 1291)
#define DPD    128
#define NK     971        // number of keys (T)
#define RPBT   244        // valid q-rows per pair (one block per pair)
#define NKT    16         // 16 key-tiles of 64 (1024 >= 971)
#define SCALE  0.08838834764831845f  // 1/sqrt(128)

typedef __attribute__((ext_vector_type(8))) short short8;
typedef __attribute__((ext_vector_type(4))) float f32x4;

__device__ __forceinline__ unsigned short f2bu(float x) {
    union { __hip_bfloat16 b; unsigned short u; } v;
    v.b = __float2bfloat16(x);
    return v.u;
}
__device__ __forceinline__ unsigned int pack2(float a, float b) {
    return (unsigned int)f2bu(a) | ((unsigned int)f2bu(b) << 16);
}

// 8 contiguous bf16 from series at element idx0 (any parity): 5 dwords + funnel shift.
__device__ __forceinline__ short8 load_sfrag(const unsigned short* s0, int idx0) {
    const unsigned int* p = (const unsigned int*)s0 + (idx0 >> 1);
    const unsigned int sh = (idx0 & 1) << 4;
    unsigned int w0 = p[0], w1 = p[1], w2 = p[2], w3 = p[3], w4 = p[4];
    union { unsigned int u[4]; short8 s; } v;
    v.u[0] = (unsigned int)((((unsigned long long)w1 << 32) | w0) >> sh);
    v.u[1] = (unsigned int)((((unsigned long long)w2 << 32) | w1) >> sh);
    v.u[2] = (unsigned int)((((unsigned long long)w3 << 32) | w2) >> sh);
    v.u[3] = (unsigned int)((((unsigned long long)w4 << 32) | w3) >> sh);
    return v.s;
}
// 8 bf16 from LDS at 8B-aligned (not 16B) address: two b64 reads.
__device__ __forceinline__ short8 ld_b64x2(const unsigned short* p) {
    union { unsigned long long q[2]; short8 s; } v;
    v.q[0] = *(const unsigned long long*)p;
    v.q[1] = *(const unsigned long long*)(p + 4);
    return v.s;
}

// Fused projection of 64 rows (16 per wave) + pe' + in-register LN -> s_kb[row][e].
__device__ __forceinline__ void proj_tile(
    const unsigned short* s_sb0, const unsigned short* s_wpb,
    const unsigned int* s_gb, unsigned short* s_kb,
    const float* __restrict__ peb,
    int widx, int perow, int rowkb, int quad, int kcol)
{
    short8 bw0 = load_sfrag(s_sb0, widx + 8 * quad);
    short8 bw1 = load_sfrag(s_sb0, widx + 32 + 8 * quad);
    f32x4 pc[8];
    #pragma unroll
    for (int mt = 0; mt < 8; ++mt) pc[mt] = (f32x4){0.f, 0.f, 0.f, 0.f};
    const int k7 = kcol & 7;
    #pragma unroll
    for (int mt = 0; mt < 8; ++mt) {
        int e = 16 * mt + kcol;
        short8 a0 = *(const short8*)&s_wpb[e * 64 + ((quad ^ k7) << 3)];
        short8 a1 = *(const short8*)&s_wpb[e * 64 + (((4 + quad) ^ k7) << 3)];
        pc[mt] = __builtin_amdgcn_mfma_f32_16x16x32_bf16(a0, bw0, pc[mt], 0, 0, 0);
        pc[mt] = __builtin_amdgcn_mfma_f32_16x16x32_bf16(a1, bw1, pc[mt], 0, 0, 0);
    }
    float x[8][4];
    float sm = 0.f, sq = 0.f;
    #pragma unroll
    for (int mt = 0; mt < 8; ++mt) {
        float4 pv = *(const float4*)&peb[perow * 128 + 16 * mt + 4 * quad];
        x[mt][0] = pc[mt][0] + pv.x; x[mt][1] = pc[mt][1] + pv.y;
        x[mt][2] = pc[mt][2] + pv.z; x[mt][3] = pc[mt][3] + pv.w;
        #pragma unroll
        for (int r = 0; r < 4; ++r) { sm += x[mt][r]; sq += x[mt][r] * x[mt][r]; }
    }
    sm += __shfl_xor(sm, 16); sq += __shfl_xor(sq, 16);
    sm += __shfl_xor(sm, 32); sq += __shfl_xor(sq, 32);
    float mean = sm * (1.0f / 128.0f);
    float var  = sq * (1.0f / 128.0f) - mean * mean;
    float rs   = rsqrtf(var + 1e-5f);
    #pragma unroll
    for (int mt = 0; mt < 8; ++mt) {
        uint4 gb = *(const uint4*)&s_gb[16 * mt + 4 * quad];
        unsigned int gw[4] = {gb.x, gb.y, gb.z, gb.w};
        float y[4];
        #pragma unroll
        for (int r = 0; r < 4; ++r) {
            float g = __uint_as_float(gw[r] << 16);
            float b = __uint_as_float(gw[r] & 0xFFFF0000u);
            y[r] = (x[mt][r] - mean) * rs * g + b;
        }
        unsigned long long w = ((unsigned long long)pack2(y[2], y[3]) << 32) | pack2(y[0], y[1]);
        *(unsigned long long*)&s_kb[rowkb * 132 + 16 * mt + 4 * quad] = w;
    }
}

// =====================================================================
// Kernel A: one block per (b,c) pair. 4 waves; wave w owns q-rows
// 64w..64w+63 (244 valid). k-projection done ONCE per pair per tile.
// grid = 512 -> 2 blocks/CU -> all resident, single CU-round.
// LDS = 71200 B. VGPR ~220 (launch_bounds(256,2)).
// =====================================================================
__global__ __launch_bounds__(256, 2)
void attn_kernel(const float* __restrict__ lookback,
                 const float* __restrict__ focal,
                 const float* __restrict__ Wp,
                 const float* __restrict__ peb,
                 const float* __restrict__ lng,
                 const float* __restrict__ lnb,
                 unsigned short* __restrict__ flat_hi,
                 unsigned short* __restrict__ flat_lo)
{
    __shared__ unsigned short s_sb0[SBLEN];     //  2592 B series bf16
    __shared__ unsigned short s_wpb[128 * 64];  // 16384 B Wp^T[e][d], XOR-swizzled
    __shared__ unsigned short s_kb[64 * 132];   // 16896 B LN'd rows [row][e]
    __shared__ unsigned short s_P[256 * 68];    // 34816 B probs [qrow][key]
    __shared__ unsigned int   s_gb[DPD];        //   512 B (g lo16, b hi16)

    const int t    = threadIdx.x;
    const int pair = blockIdx.x;
    const int lane = t & 63;
    const int wave = t >> 6;
    const int quad = lane >> 4;
    const int kcol = lane & 15;

    // ---------------- init ----------------
    {
        if (t < 256) {
            float4 v = ((const float4*)(lookback + pair * LOOK))[t];
            s_sb0[4 * t]     = f2bu(v.x);
            s_sb0[4 * t + 1] = f2bu(v.y);
            s_sb0[4 * t + 2] = f2bu(v.z);
            s_sb0[4 * t + 3] = f2bu(v.w);
        }
        if (t < 64) {
            float4 v = ((const float4*)(focal + pair * PREDN))[t];
            s_sb0[LOOK + 4 * t]     = f2bu(v.x);
            s_sb0[LOOK + 4 * t + 1] = f2bu(v.y);
            s_sb0[LOOK + 4 * t + 2] = f2bu(v.z);
            s_sb0[LOOK + 4 * t + 3] = f2bu(v.w);
        }
        if (t < SBLEN - TOT) s_sb0[TOT + t] = 0;
        #pragma unroll
        for (int j = 0; j < 32; ++j) {            // Wp[k][e] -> swizzled Wp^T
            int fl = j * 256 + t;
            int k = fl >> 7, e = fl & 127;
            s_wpb[e * 64 + (((k >> 3) ^ (e & 7)) << 3) + (k & 7)] = f2bu(Wp[fl]);
        }
        if (t < DPD)
            s_gb[t] = (unsigned int)f2bu(lng[t]) | ((unsigned int)f2bu(lnb[t]) << 16);
    }
    __syncthreads();

    // ---------------- q: 4 tiles of 64 rows; wave w keeps tile qt==w ----
    short8 aq[4][4];   // wave's 64 q-rows as MFMA B-frags [ntQ][kc]
    for (int qt = 0; qt < 4; ++qt) {
        proj_tile(s_sb0, s_wpb, s_gb, s_kb, peb,
                  972 + 64 * qt + 16 * wave + kcol,
                  971 + 64 * qt + 16 * wave + kcol,   // peb row <= 1226 < 1280
                  16 * wave + kcol, quad, kcol);
        __syncthreads();
        if (wave == qt) {
            #pragma unroll
            for (int ntQ = 0; ntQ < 4; ++ntQ)
                #pragma unroll
                for (int kc = 0; kc < 4; ++kc)
                    aq[ntQ][kc] = ld_b64x2(&s_kb[(16 * ntQ + kcol) * 132 + 32 * kc + 8 * quad]);
        }
        __syncthreads();
    }

    float mrow[4] = {-3.0e38f, -3.0e38f, -3.0e38f, -3.0e38f};
    float lrow[4] = {0.0f, 0.0f, 0.0f, 0.0f};
    f32x4 o[4][4];
    #pragma unroll
    for (int a = 0; a < 4; ++a)
        #pragma unroll
        for (int b = 0; b < 4; ++b) o[a][b] = (f32x4){0.f, 0.f, 0.f, 0.f};

    // ---------------- main loop: 16 tiles of 64 keys ----------------
    for (int tile = 0; tile < NKT; ++tile) {
        const int j0 = tile * 64;

        proj_tile(s_sb0, s_wpb, s_gb, s_kb, peb,
                  j0 + 16 * wave + kcol, j0 + 16 * wave + kcol,
                  16 * wave + kcol, quad, kcol);
        __syncthreads();   // B1: k-tile ready

        // QK^T (S^T): D[key][qrow]; A = k rows (shared), B = aq
        f32x4 sacc[4][4];
        #pragma unroll
        for (int a = 0; a < 4; ++a)
            #pragma unroll
            for (int b = 0; b < 4; ++b) sacc[a][b] = (f32x4){0.f, 0.f, 0.f, 0.f};
        #pragma unroll
        for (int kc = 0; kc < 4; ++kc) {
            short8 ak[4];
            #pragma unroll
            for (int mtK = 0; mtK < 4; ++mtK)
                ak[mtK] = ld_b64x2(&s_kb[(16 * mtK + kcol) * 132 + 32 * kc + 8 * quad]);
            #pragma unroll
            for (int ntQ = 0; ntQ < 4; ++ntQ)
                #pragma unroll
                for (int mtK = 0; mtK < 4; ++mtK)
                    sacc[ntQ][mtK] = __builtin_amdgcn_mfma_f32_16x16x32_bf16(
                        ak[mtK], aq[ntQ][kc], sacc[ntQ][mtK], 0, 0, 0);
        }

        // online softmax: per lane 4 q-rows (qrow = 64w+16ntQ+kcol)
        float alf[4];
        #pragma unroll
        for (int ntQ = 0; ntQ < 4; ++ntQ) {
            float P[4][4];
            float mx = -1.0e30f;
            #pragma unroll
            for (int mtK = 0; mtK < 4; ++mtK)
                #pragma unroll
                for (int r = 0; r < 4; ++r) {
                    int key = j0 + 16 * mtK + 4 * quad + r;
                    float s = (key < NK) ? sacc[ntQ][mtK][r] * SCALE : -1.0e30f;
                    P[mtK][r] = s;
                    mx = fmaxf(mx, s);
                }
            mx = fmaxf(mx, __shfl_xor(mx, 16));
            mx = fmaxf(mx, __shfl_xor(mx, 32));
            float mo = mrow[ntQ];
            float mn = fmaxf(mo, mx);
            float a  = __expf(mo - mn);
            float ss = 0.f;
            #pragma unroll
            for (int mtK = 0; mtK < 4; ++mtK)
                #pragma unroll
                for (int r = 0; r < 4; ++r) {
                    P[mtK][r] = __expf(P[mtK][r] - mn);
                    ss += P[mtK][r];
                }
            ss += __shfl_xor(ss, 16);
            ss += __shfl_xor(ss, 32);
            lrow[ntQ] = lrow[ntQ] * a + ss;
            mrow[ntQ] = mn;
            alf[ntQ]  = a;
            const int pbase = (16 * (4 * wave + ntQ) + kcol) * 68;
            #pragma unroll
            for (int mtK = 0; mtK < 4; ++mtK) {
                unsigned long long w = ((unsigned long long)pack2(P[mtK][2], P[mtK][3]) << 32)
                                       | pack2(P[mtK][0], P[mtK][1]);
                *(unsigned long long*)&s_P[pbase + 16 * mtK + 4 * quad] = w;
            }
        }

        // rescale O by alpha (state lane -> accumulator lane via shuffle)
        #pragma unroll
        for (int ntQ = 0; ntQ < 4; ++ntQ)
            #pragma unroll
            for (int r = 0; r < 4; ++r) {
                float af = __shfl(alf[ntQ], 20 * quad + r);
                #pragma unroll
                for (int ntD = 0; ntD < 4; ++ntD) o[ntQ][ntD][r] *= af;
            }

        // PV: A = P (wave-local rows of s_P), B = X^T straight from series
        short8 xf[4][2];
        #pragma unroll
        for (int ntD = 0; ntD < 4; ++ntD)
            #pragma unroll
            for (int kc2 = 0; kc2 < 2; ++kc2)
                xf[ntD][kc2] = load_sfrag(s_sb0, j0 + 1 + 32 * kc2 + 8 * quad + 16 * ntD + kcol);
        #pragma unroll
        for (int ntQ = 0; ntQ < 4; ++ntQ) {
            const int pbase = (16 * (4 * wave + ntQ) + kcol) * 68;
            short8 ap[2];
            #pragma unroll
            for (int kc2 = 0; kc2 < 2; ++kc2)
                ap[kc2] = ld_b64x2(&s_P[pbase + 32 * kc2 + 8 * quad]);
            #pragma unroll
            for (int ntD = 0; ntD < 4; ++ntD)
                #pragma unroll
                for (int kc2 = 0; kc2 < 2; ++kc2)
                    o[ntQ][ntD] = __builtin_amdgcn_mfma_f32_16x16x32_bf16(
                        ap[kc2], xf[ntD][kc2], o[ntQ][ntD], 0, 0, 0);
        }
        __syncthreads();   // B2: s_kb free for next tile
    }

    // ---------------- epilogue: hi/lo bf16 split store ----------------
    float inv[4] = {1.0f / lrow[0], 1.0f / lrow[1], 1.0f / lrow[2], 1.0f / lrow[3]};
    #pragma unroll
    for (int ntQ = 0; ntQ < 4; ++ntQ)
        #pragma unroll
        for (int r = 0; r < 4; ++r) {
            float li = __shfl(inv[ntQ], 20 * quad + r);
            int brow = 64 * wave + 16 * ntQ + 4 * quad + r;
            if (brow < RPBT) {
                int base = pair * 15616 + brow * 64 + kcol;
                #pragma unroll
                for (int ntD = 0; ntD < 4; ++ntD) {
                    float v = o[ntQ][ntD][r] * li;
                    unsigned short h = f2bu(v);
                    float vh = __uint_as_float((unsigned int)h << 16);
                    flat_hi[base + 16 * ntD] = h;
                    flat_lo[base + 16 * ntD] = f2bu(v - vh);
                }
            }
        }
}

// =====================================================================
// Kernel P: peb = pe + bp (folded bias), 1280x128.
// =====================================================================
__global__ void peb_kernel(const float* __restrict__ pe,
                           const float* __restrict__ bp,
                           float* __restrict__ peb)
{
    int i = blockIdx.x * 256 + threadIdx.x;   // 163840
    peb[i] = pe[i] + bp[i & 127];
}

// =====================================================================
// Kernel B: mlp1 = flat(512x15616) @ W1(15616x256), bf16 MFMA hi/lo
// 3-pass. grid = 256 (4m(128) x 4n(64) x 16 k-splits).
// =====================================================================
__global__ __launch_bounds__(256, 2)
void mlp1_kernel(const unsigned short* __restrict__ Ah,
                 const unsigned short* __restrict__ Al,
                 const float* __restrict__ W1,
                 float* __restrict__ part)
{
    const int bid = blockIdx.x;
    const int bm = bid & 3, bn = (bid >> 2) & 3, bz = bid >> 4;
    const int m0 = bm * 128, n0 = bn * 64;
    const int t0 = bz * 30 + (bz < 8 ? bz : 8);   // 488 k-tiles of 32 total
    const int nt = (bz < 8) ? 31 : 30;

    __shared__ unsigned short sAh[128 * 40];  // [m][k], pad 8
    __shared__ unsigned short sAl[128 * 40];
    __shared__ unsigned short sBh[64 * 44];   // [n][k] (W1^T), pad 12
    __shared__ unsigned short sBl[64 * 44];

    const int t = threadIdx.x;
    const int wv = t >> 6, lane = t & 63;
    const int quad = lane >> 4, kcol = lane & 15;
    const int ar = t >> 1, ac16 = (t & 1) * 16;   // A staging: 128 rows x 32 k
    const int bk = t >> 3, bn8 = (t & 7) * 8;     // B staging: 32 k x 64 n

    f32x4 acc[8];
    #pragma unroll
    for (int i = 0; i < 8; ++i) acc[i] = (f32x4){0.f, 0.f, 0.f, 0.f};

    for (int tt = 0; tt < nt; ++tt) {
        const int kc = (t0 + tt) * 32;
        *(uint4*)&sAh[ar * 40 + ac16]     = *(const uint4*)(Ah + (m0 + ar) * 15616 + kc + ac16);
        *(uint4*)&sAh[ar * 40 + ac16 + 8] = *(const uint4*)(Ah + (m0 + ar) * 15616 + kc + ac16 + 8);
        *(uint4*)&sAl[ar * 40 + ac16]     = *(const uint4*)(Al + (m0 + ar) * 15616 + kc + ac16);
        *(uint4*)&sAl[ar * 40 + ac16 + 8] = *(const uint4*)(Al + (m0 + ar) * 15616 + kc + ac16 + 8);
        {
            const float* wp = W1 + (kc + bk) * 256 + n0 + bn8;
            float4 wa = *(const float4*)wp;
            float4 wb = *(const float4*)(wp + 4);
            float vv[8] = {wa.x, wa.y, wa.z, wa.w, wb.x, wb.y, wb.z, wb.w};
            #pragma unroll
            for (int i = 0; i < 8; ++i) {
                unsigned short h = f2bu(vv[i]);
                float vh = __uint_as_float((unsigned int)h << 16);
                sBh[(bn8 + i) * 44 + bk] = h;
                sBl[(bn8 + i) * 44 + bk] = f2bu(vv[i] - vh);
            }
        }
        __syncthreads();
        short8 bh = ld_b64x2(&sBh[(16 * wv + kcol) * 44 + quad * 8]);
        short8 bl = ld_b64x2(&sBl[(16 * wv + kcol) * 44 + quad * 8]);
        #pragma unroll
        for (int mt = 0; mt < 8; ++mt) {
            short8 ah = *(const short8*)&sAh[(16 * mt + kcol) * 40 + quad * 8];
            short8 al = *(const short8*)&sAl[(16 * mt + kcol) * 40 + quad * 8];
            acc[mt] = __builtin_amdgcn_mfma_f32_16x16x32_bf16(ah, bh, acc[mt], 0, 0, 0);
            acc[mt] = __builtin_amdgcn_mfma_f32_16x16x32_bf16(al, bh, acc[mt], 0, 0, 0);
            acc[mt] = __builtin_amdgcn_mfma_f32_16x16x32_bf16(ah, bl, acc[mt], 0, 0, 0);
        }
        __syncthreads();
    }
    float* dst = part + bz * (512 * 256);
    #pragma unroll
    for (int mt = 0; mt < 8; ++mt)
        #pragma unroll
        for (int r = 0; r < 4; ++r)
            dst[(m0 + 16 * mt + 4 * quad + r) * 256 + n0 + 16 * wv + kcol] = acc[mt][r];
}

// =====================================================================
// Kernel C: reduce 16 partials + bias + exact GELU -> H (512x256).
// =====================================================================
__global__ void gelu_kernel(const float* __restrict__ part,
                            const float* __restrict__ b1,
                            float* __restrict__ H)
{
    const int i = blockIdx.x * 256 + threadIdx.x;
    float s = 0.0f;
    #pragma unroll
    for (int ks = 0; ks < 16; ++ks) s += part[ks * 131072 + i];
    s += b1[i & 255];
    H[i] = 0.5f * s * (1.0f + erff(s * 0.7071067811865475f));
}

// =====================================================================
// Kernel D: out = H(512x256) @ W2(256x256) + b2 (fp32 out).
// =====================================================================
__global__ __launch_bounds__(256, 2)
void mlp2_kernel(const float* __restrict__ H,
                 const float* __restrict__ W2,
                 const float* __restrict__ b2,
                 float* __restrict__ out)
{
    const int bm = blockIdx.x & 7, bn = blockIdx.x >> 3;
    const int m0 = bm * 64, n0 = bn * 64;
    __shared__ float sA[64 * 36];
    __shared__ float sB[32 * 68];
    float acc[16];
    #pragma unroll
    for (int i = 0; i < 16; ++i) acc[i] = 0.0f;

    const int wv = threadIdx.x >> 6, ln = threadIdx.x & 63;
    const int tm = 4 * wv + (ln >> 4), tn = ln & 15;
    const int r = threadIdx.x >> 3;
    const int c4 = (threadIdx.x & 7) * 4;
    const int c8 = (threadIdx.x & 7) * 8;

    for (int tt = 0; tt < 8; ++tt) {
        const int kc = tt * 32;
        *(float4*)&sA[r * 36 + c4]        = *(const float4*)(H + (m0 + r) * 256 + kc + c4);
        *(float4*)&sA[(r + 32) * 36 + c4] = *(const float4*)(H + (m0 + r + 32) * 256 + kc + c4);
        *(float4*)&sB[r * 68 + c8]     = *(const float4*)(W2 + (kc + r) * 256 + n0 + c8);
        *(float4*)&sB[r * 68 + c8 + 4] = *(const float4*)(W2 + (kc + r) * 256 + n0 + c8 + 4);
        __syncthreads();
        #pragma unroll
        for (int kg = 0; kg < 8; ++kg) {
            float4 a[4], b[4];
            #pragma unroll
            for (int i = 0; i < 4; ++i) a[i] = *(const float4*)&sA[(4 * tm + i) * 36 + 4 * kg];
            #pragma unroll
            for (int j = 0; j < 4; ++j) b[j] = *(const float4*)&sB[(4 * kg + j) * 68 + 4 * tn];
            #pragma unroll
            for (int i = 0; i < 4; ++i) {
                acc[4*i+0] += a[i].x*b[0].x + a[i].y*b[1].x + a[i].z*b[2].x + a[i].w*b[3].x;
                acc[4*i+1] += a[i].x*b[0].y + a[i].y*b[1].y + a[i].z*b[2].y + a[i].w*b[3].y;
                acc[4*i+2] += a[i].x*b[0].z + a[i].y*b[1].z + a[i].z*b[2].z + a[i].w*b[3].z;
                acc[4*i+3] += a[i].x*b[0].w + a[i].y*b[1].w + a[i].z*b[2].w + a[i].w*b[3].w;
            }
        }
        __syncthreads();
    }
    #pragma unroll
    for (int i = 0; i < 4; ++i)
        #pragma unroll
        for (int j = 0; j < 4; ++j) {
            const int m = m0 + 4 * tm + i, n = n0 + 4 * tn + j;
            out[m * 256 + n] = acc[4 * i + j] + b2[n];
        }
}

extern "C" void kernel_launch(void* const* d_in, const int* in_sizes, int n_in,
                              void* d_out, int out_size, void* d_ws, size_t ws_size,
                              hipStream_t stream) {
    (void)in_sizes; (void)n_in; (void)out_size; (void)ws_size;
    const float* lookback = (const float*)d_in[0];
    const float* focal    = (const float*)d_in[1];
    const float* Wp       = (const float*)d_in[2];
    const float* bp       = (const float*)d_in[3];
    const float* pe       = (const float*)d_in[4];
    const float* lng      = (const float*)d_in[5];
    const float* lnb      = (const float*)d_in[6];
    const float* W1       = (const float*)d_in[7];
    const float* b1       = (const float*)d_in[8];
    const float* W2       = (const float*)d_in[9];
    const float* b2       = (const float*)d_in[10];

    unsigned short* flat_hi = (unsigned short*)d_ws;        // 512*15616 bf16 (16 MB)
    unsigned short* flat_lo = flat_hi + 512 * 15616;        // 16 MB
    float* part = (float*)(flat_lo + 512 * 15616);          // 16*512*256 f32 (8 MB)
    float* H    = part + 16 * 512 * 256;                    // 0.5 MB
    float* peb  = part;   // alias: read by attn, overwritten later by mlp1

    hipLaunchKernelGGL(peb_kernel, dim3(640), dim3(256), 0, stream, pe, bp, peb);
    hipLaunchKernelGGL(attn_kernel, dim3(512), dim3(256), 0, stream,
                       lookback, focal, Wp, peb, lng, lnb, flat_hi, flat_lo);
    hipLaunchKernelGGL(mlp1_kernel, dim3(256), dim3(256), 0, stream,
                       flat_hi, flat_lo, W1, part);
    hipLaunchKernelGGL(gelu_kernel, dim3(512), dim3(256), 0, stream, part, b1, H);
    hipLaunchKernelGGL(mlp2_kernel, dim3(32), dim3(256), 0, stream, H, W2, b2,
                       (float*)d_out);
}